// Round 12
// baseline (1349.159 us; speedup 1.0000x reference)
//
#include <hip/hip_runtime.h>
#include <hip/hip_bf16.h>
#include <math.h>

// Problem constants
#define B_  64
#define W_  128
#define L_  32
#define V_  128
#define E_  128
#define H_  256
#define G4_ 1024      // 4*H
#define NW  8192      // B*W words
#define KS_ 8         // MFMA k-steps: h only (K=256)
#define KPAD 264      // padded LDS row (bf16): 256 used + 8 pad (528B = 33*16B, odd)
#define M_  64        // words per block (16 waves, 1 block/CU)

typedef short s8v  __attribute__((ext_vector_type(8)));  // 8 bf16 (4 VGPR)
typedef float f4v  __attribute__((ext_vector_type(4)));

static __device__ __forceinline__ float b2f(unsigned short u) {
  return __uint_as_float(((unsigned int)u) << 16);
}

// ---------------------------------------------------------------------------
// K1: ep4[dir][v][col][gate] = bf16( dot(emb[v], Wih_dir[gate*256+col]) + biases )
// gate-last ushort4: one 8B load gives all 4 gate pre-activations.
// ---------------------------------------------------------------------------
__global__ __launch_bounds__(256) void k_embproj(
    const float* __restrict__ emb,
    const float* __restrict__ Wih_f, const float* __restrict__ bih_f, const float* __restrict__ bhh_f,
    const float* __restrict__ Wih_b, const float* __restrict__ bih_b, const float* __restrict__ bhh_b,
    unsigned short* __restrict__ ep4) {
  int v   = blockIdx.x & (V_ - 1);
  int dir = blockIdx.x >> 7;
  const float* Wih = dir ? Wih_b : Wih_f;
  const float* b1  = dir ? bih_b : bih_f;
  const float* b2  = dir ? bhh_b : bhh_f;
  __shared__ float es[E_];
  if (threadIdx.x < E_) es[threadIdx.x] = emb[v * E_ + threadIdx.x];
  __syncthreads();
#pragma unroll
  for (int q = 0; q < 4; ++q) {
    int g = q * 256 + threadIdx.x;       // g = gate*256 + col
    const float* wr = Wih + g * E_;
    float a = 0.f;
#pragma unroll 4
    for (int k = 0; k < E_; k += 4) {
      float4 w4 = *(const float4*)(wr + k);
      float4 e4 = *(const float4*)(es + k);
      a += w4.x * e4.x + w4.y * e4.y + w4.z * e4.z + w4.w * e4.w;
    }
    int gate = g >> 8, col = g & 255;
    union { __hip_bfloat16 b; unsigned short u; } cv;
    cv.b = __float2bfloat16(a + b1[g] + b2[g]);
    ep4[((((dir * V_ + v) << 8) + col) << 2) + gate] = cv.u;
  }
}

// ---------------------------------------------------------------------------
// K1b: pack Whh^T (256 x 1024) per dir into per-WAVE-contiguous MFMA
// B-fragment layout for 16 waves:  Bpack[dir][ks][w(16)][u(4)][lane][8]  (bf16)
//   nt = u*16 + w   (wave w owns ONE column tile per gate group u)
//   elem j: Bmat[k][n] = Whh[n][k], k = ks*32 + (lane>>4)*8 + j,
//                                   n = nt*16 + (lane&15)
// Per (ks,w) a wave's 4 fragments are one contiguous 4KB chunk.
// ---------------------------------------------------------------------------
__global__ __launch_bounds__(64) void k_pack(
    const float* __restrict__ Whh_f, const float* __restrict__ Whh_b,
    __hip_bfloat16* __restrict__ Bpack) {
  const int lane = threadIdx.x;
  const int u    = blockIdx.x & 3;
  const int w    = (blockIdx.x >> 2) & 15;
  const int ks   = (blockIdx.x >> 6) & 7;
  const int dir  = blockIdx.x >> 9;
  const float* Whh = dir ? Whh_b : Whh_f;
  const int nt = u * 16 + w;
  const int n  = nt * 16 + (lane & 15);
  const int k0 = ks * 32 + (lane >> 4) * 8;
  size_t base = ((((size_t)(dir * KS_ + ks) * 16 + w) * 4 + u) * 64 + lane) * 8;
#pragma unroll
  for (int j = 0; j < 8; ++j)
    Bpack[base + j] = __float2bfloat16(Whh[n * H_ + k0 + j]);
}

// ---------------------------------------------------------------------------
// K1c: deterministic stable counting sort of words by length, DESCENDING.
// ---------------------------------------------------------------------------
#define NCHUNK 8
#define CHSZ  (NW / NCHUNK)
__global__ __launch_bounds__(256) void k_sort(const int* __restrict__ word_lens,
                                              int* __restrict__ perm) {
  __shared__ int cnt_s[NCHUNK][33];
  __shared__ int off_s[NCHUNK][33];
  const int tid = threadIdx.x;
  const int ch  = tid >> 5;
  const int ln  = (tid & 31) + 1;   // 1..32
  const int base = ch * CHSZ;
  int c = 0;
  for (int i = 0; i < CHSZ; ++i) c += (word_lens[base + i] == ln);
  cnt_s[ch][ln] = c;
  __syncthreads();
  if (tid == 0) {
    int run = 0;
    for (int l = 32; l >= 1; --l)
      for (int c2 = 0; c2 < NCHUNK; ++c2) { off_s[c2][l] = run; run += cnt_s[c2][l]; }
  }
  __syncthreads();
  int ptr = off_s[ch][ln];
  for (int i = 0; i < CHSZ; ++i) {
    int wi = base + i;
    if (word_lens[wi] == ln) perm[ptr++] = wi;
  }
}

// ---------------------------------------------------------------------------
// K2: MFMA BiLSTM recurrence. Block = 64 sorted words x 1 dir, 16 waves
// (1024 thr), 256 blocks = 1 block/CU.  Wave w owns gate-cols nt = u*16+w.
// Per-thread acc[u][mt] = 64 f32 (same shape as the proven r8 allocation ->
// AGPRs).  EXACT r8 phase structure: [MFMA reads hL] -> sync -> [gather ep4 +
// elementwise, conditional h write to hL] -> sync.  Two barriers; single hL.
// C/D layout (verified m89): word = mt*16 + (lane>>4)*4 + r, col = nt*16+(lane&15)
//   -> position p = w*16 + (lane&15) is the SAME for all 4 gates (col = u*256+p).
// ---------------------------------------------------------------------------
__global__ __launch_bounds__(1024, 1) void k_lstm(
    const int* __restrict__ char_ids, const int* __restrict__ word_lens,
    const int* __restrict__ perm, const unsigned short* __restrict__ ep4,
    const __hip_bfloat16* __restrict__ Bpack, unsigned short* __restrict__ hcat) {
  const int tid  = threadIdx.x;
  const int lane = tid & 63;
  const int w    = tid >> 6;       // wave 0..15
  const int bid  = blockIdx.x;
  const int dir  = bid & 1;
  const int w0   = (bid >> 1) * M_;

  __shared__ unsigned short hL[M_][KPAD];  // 33.8 KB
  __shared__ int ids_s[M_][L_ + 1];        // 8.4 KB
  __shared__ int len_s[M_];
  __shared__ int pw_s[M_];

  if (tid < M_) {
    int gw = perm[w0 + tid];
    pw_s[tid]  = gw;
    len_s[tid] = word_lens[gw];
  }
  __syncthreads();
  for (int i = tid; i < M_ * L_; i += 1024) {
    int q = i >> 5;
    ids_s[q][i & 31] = char_ids[pw_s[q] * L_ + (i & 31)];
  }
  for (int i = tid; i < M_ * KPAD / 2; i += 1024) ((unsigned int*)hL)[i] = 0u;
  __syncthreads();

  const int mlen = len_s[0];   // descending stable sort -> first word is longest
  unsigned lrp[4];
#pragma unroll
  for (int mt = 0; mt < 4; ++mt) {
    int bw = mt * 16 + ((lane >> 4) << 2);
    lrp[mt] = (unsigned)len_s[bw] | ((unsigned)len_s[bw + 1] << 8) |
              ((unsigned)len_s[bw + 2] << 16) | ((unsigned)len_s[bw + 3] << 24);
  }

  // per-dir, per-wave B base: Bpack[dir][ks=0][w][0][lane][0]; ks stride 64KB
  const char* Bb0 = (const char*)Bpack + (size_t)dir * (KS_ * 16 * 4 * 64 * 16)
                    + (size_t)w * (4 * 64 * 16) + (size_t)lane * 16;
  // A-frag base: frag(mt,ks) at ar + mt*8448 + ks*64  (imm offsets)
  const char* ar = (const char*)&hL[lane & 15][0] + ((lane >> 4) << 4);
  const ushort4* epv = (const ushort4*)ep4 + ((size_t)dir << 15);  // dir*V*256
  const int p  = w * 16 + (lane & 15);     // position (0..255), all 4 gates
  const int g4 = (lane >> 4) << 2;

  float c_[4][4];                          // [mt][r]
#pragma unroll
  for (int mt = 0; mt < 4; ++mt)
#pragma unroll
    for (int r = 0; r < 4; ++r) c_[mt][r] = 0.f;

  for (int t = 0; t < mlen; ++t) {
    // --- MFMA phase: reads hL ---
    f4v acc[4][4];                         // [gate u][mt]
#pragma unroll
    for (int u = 0; u < 4; ++u)
#pragma unroll
      for (int mt = 0; mt < 4; ++mt) acc[u][mt] = (f4v){0.f, 0.f, 0.f, 0.f};

    const char* bp = Bb0;                  // 4 frags (imm offs 0..3072)
#pragma unroll
    for (int ks = 0; ks < KS_; ++ks) {
      s8v af0 = *(const s8v*)(ar + 0     + ks * 64);
      s8v af1 = *(const s8v*)(ar + 8448  + ks * 64);
      s8v af2 = *(const s8v*)(ar + 16896 + ks * 64);
      s8v af3 = *(const s8v*)(ar + 25344 + ks * 64);
      s8v b0 = *(const s8v*)(bp + 0);
      s8v b1 = *(const s8v*)(bp + 1024);
      s8v b2 = *(const s8v*)(bp + 2048);
      s8v b3 = *(const s8v*)(bp + 3072);
      acc[0][0] = __builtin_amdgcn_mfma_f32_16x16x32_bf16(af0, b0, acc[0][0], 0, 0, 0);
      acc[0][1] = __builtin_amdgcn_mfma_f32_16x16x32_bf16(af1, b0, acc[0][1], 0, 0, 0);
      acc[0][2] = __builtin_amdgcn_mfma_f32_16x16x32_bf16(af2, b0, acc[0][2], 0, 0, 0);
      acc[0][3] = __builtin_amdgcn_mfma_f32_16x16x32_bf16(af3, b0, acc[0][3], 0, 0, 0);
      acc[1][0] = __builtin_amdgcn_mfma_f32_16x16x32_bf16(af0, b1, acc[1][0], 0, 0, 0);
      acc[1][1] = __builtin_amdgcn_mfma_f32_16x16x32_bf16(af1, b1, acc[1][1], 0, 0, 0);
      acc[1][2] = __builtin_amdgcn_mfma_f32_16x16x32_bf16(af2, b1, acc[1][2], 0, 0, 0);
      acc[1][3] = __builtin_amdgcn_mfma_f32_16x16x32_bf16(af3, b1, acc[1][3], 0, 0, 0);
      acc[2][0] = __builtin_amdgcn_mfma_f32_16x16x32_bf16(af0, b2, acc[2][0], 0, 0, 0);
      acc[2][1] = __builtin_amdgcn_mfma_f32_16x16x32_bf16(af1, b2, acc[2][1], 0, 0, 0);
      acc[2][2] = __builtin_amdgcn_mfma_f32_16x16x32_bf16(af2, b2, acc[2][2], 0, 0, 0);
      acc[2][3] = __builtin_amdgcn_mfma_f32_16x16x32_bf16(af3, b2, acc[2][3], 0, 0, 0);
      acc[3][0] = __builtin_amdgcn_mfma_f32_16x16x32_bf16(af0, b3, acc[3][0], 0, 0, 0);
      acc[3][1] = __builtin_amdgcn_mfma_f32_16x16x32_bf16(af1, b3, acc[3][1], 0, 0, 0);
      acc[3][2] = __builtin_amdgcn_mfma_f32_16x16x32_bf16(af2, b3, acc[3][2], 0, 0, 0);
      acc[3][3] = __builtin_amdgcn_mfma_f32_16x16x32_bf16(af3, b3, acc[3][3], 0, 0, 0);
      bp += 65536;   // ks stride = 16w * 4u * 64lane * 16B
    }

    __syncthreads();   // all waves done reading hL for step t

    // --- elementwise: gather ep4, gates, conditional state update ---
#pragma unroll
    for (int mt = 0; mt < 4; ++mt) {
      const int mbase = mt * 16 + g4;
      ushort4 xw[4];
#pragma unroll
      for (int r = 0; r < 4; ++r) {
        int len = (int)((lrp[mt] >> (8 * r)) & 255u);
        int tt  = dir ? max(len - 1 - t, 0) : t;   // t < mlen <= 32 in-bounds
        int id  = ids_s[mbase + r][tt];
        xw[r] = epv[(id << 8) + p];
      }
#pragma unroll
      for (int r = 0; r < 4; ++r) {
        float gi = acc[0][mt][r] + b2f(xw[r].x);
        float gf = acc[1][mt][r] + b2f(xw[r].y);
        float gg = acc[2][mt][r] + b2f(xw[r].z);
        float go = acc[3][mt][r] + b2f(xw[r].w);
        float si = 1.f / (1.f + __expf(-gi));
        float sf = 1.f / (1.f + __expf(-gf));
        float so = 1.f / (1.f + __expf(-go));
        float tg = 2.f / (1.f + __expf(-2.f * gg)) - 1.f;
        float cn = sf * c_[mt][r] + si * tg;
        float hn = so * (2.f / (1.f + __expf(-2.f * cn)) - 1.f);
        int  len = (int)((lrp[mt] >> (8 * r)) & 255u);
        if (t < len) {
          c_[mt][r] = cn;
          union { __hip_bfloat16 b; unsigned short u; } cv;
          cv.b = __float2bfloat16(hn);
          hL[mbase + r][p] = cv.u;
        }
      }
    }
    __syncthreads();   // h(t+1) visible before next MFMA phase
  }

  // write frozen h (bf16) to hcat at ORIGINAL word position: [h_bwd | h_fwd]
  const int off = dir ? 0 : H_;
  for (int i = tid; i < M_ * H_ / 8; i += 1024) {   // 2048 vec8 chunks, 2 iters
    int q   = i >> 5;              // local word
    int pos = (i & 31) << 3;       // col (multiple of 8)
    s8v v = *(const s8v*)&hL[q][pos];
    *(s8v*)&hcat[(size_t)pw_s[q] * (2 * H_) + off + pos] = v;
  }
}

// ---------------------------------------------------------------------------
// K3: wemb = hcat(bf16) @ pW^T + pb;  also writes lens_out (= W) slots.
// ---------------------------------------------------------------------------
#define PM_ 16
__global__ __launch_bounds__(256) void k_proj(
    const unsigned short* __restrict__ hcat, const float* __restrict__ pW,
    const float* __restrict__ pb, float* __restrict__ out) {
  const int tid = threadIdx.x;
  const int n0  = blockIdx.x * PM_;
  __shared__ float hs[PM_][2 * H_];   // 32 KB
  for (int i = tid; i < PM_ * 2 * H_; i += 256) {
    unsigned int ui = ((unsigned int)hcat[(size_t)n0 * 2 * H_ + i]) << 16;
    ((float*)hs)[i] = __uint_as_float(ui);
  }
  __syncthreads();

  const float* pwr = pW + tid * (2 * H_);
  float acc[PM_];
#pragma unroll
  for (int m = 0; m < PM_; ++m) acc[m] = 0.f;

#pragma unroll 2
  for (int k = 0; k < 2 * H_; k += 4) {
    float4 w4 = *(const float4*)(pwr + k);
#pragma unroll
    for (int m = 0; m < PM_; ++m) {
      float4 h4 = *(const float4*)(&hs[m][k]);
      acc[m] += w4.x * h4.x + w4.y * h4.y + w4.z * h4.z + w4.w * h4.w;
    }
  }
  const float bias = pb[tid];
#pragma unroll
  for (int m = 0; m < PM_; ++m) out[(n0 + m) * H_ + tid] = acc[m] + bias;

  if (blockIdx.x == 0 && tid < B_) out[NW * H_ + tid] = (float)W_;
}

// ---------------------------------------------------------------------------
extern "C" void kernel_launch(void* const* d_in, const int* in_sizes, int n_in,
                              void* d_out, int out_size, void* d_ws, size_t ws_size,
                              hipStream_t stream) {
  const int*   char_ids  = (const int*)  d_in[0];
  const int*   word_lens = (const int*)  d_in[1];
  const float* emb       = (const float*)d_in[2];
  const float* Wih_f     = (const float*)d_in[3];
  const float* Whh_f     = (const float*)d_in[4];
  const float* bih_f     = (const float*)d_in[5];
  const float* bhh_f     = (const float*)d_in[6];
  const float* Wih_b     = (const float*)d_in[7];
  const float* Whh_b     = (const float*)d_in[8];
  const float* bih_b     = (const float*)d_in[9];
  const float* bhh_b     = (const float*)d_in[10];
  const float* pW        = (const float*)d_in[11];
  const float* pb        = (const float*)d_in[12];
  float* out = (float*)d_out;

  // ws layout: [Bpack 1MB][ep4(bf16) 512KB][perm 32KB][hcat(bf16) 8.4MB]
  const size_t BPACK_BYTES = (size_t)2 * KS_ * 16 * 4 * 64 * 8 * 2;  // 1 MB
  const size_t EP4_BYTES   = (size_t)2 * V_ * 256 * 4 * 2;           // 512 KB
  __hip_bfloat16* Bpack = (__hip_bfloat16*)d_ws;
  unsigned short* ep4 = (unsigned short*)((char*)d_ws + BPACK_BYTES);
  int* perm = (int*)((char*)d_ws + BPACK_BYTES + EP4_BYTES);
  unsigned short* hcat = (unsigned short*)((char*)d_ws + BPACK_BYTES + EP4_BYTES + NW * sizeof(int));

  k_sort<<<dim3(1), dim3(256), 0, stream>>>(word_lens, perm);
  k_embproj<<<dim3(2 * V_), dim3(256), 0, stream>>>(emb, Wih_f, bih_f, bhh_f,
                                                    Wih_b, bih_b, bhh_b, ep4);
  k_pack<<<dim3(2 * KS_ * 16 * 4), dim3(64), 0, stream>>>(Whh_f, Whh_b, Bpack);
  k_lstm<<<dim3(2 * NW / M_), dim3(1024), 0, stream>>>(char_ids, word_lens, perm, ep4, Bpack, hcat);
  k_proj<<<dim3(NW / PM_), dim3(256), 0, stream>>>(hcat, pW, pb, out);
}

// Round 13
// 699.894 us; speedup vs baseline: 1.9277x; 1.9277x over previous
//
#include <hip/hip_runtime.h>
#include <hip/hip_bf16.h>
#include <hip/hip_fp8.h>
#include <math.h>

// Problem constants
#define B_  64
#define W_  128
#define L_  32
#define V_  128
#define E_  128
#define H_  256
#define G4_ 1024      // 4*H
#define NW  8192      // B*W words
#define KS_ 8         // MFMA k-steps: h only (K=256), K=32 per fp8 MFMA
#define ROWB 264      // hL row bytes: 256 fp8 + 8 pad (33*8, odd*8 -> bank spread)
#define M_  32        // words per block

typedef long i64;
typedef float f4v  __attribute__((ext_vector_type(4)));

static __device__ __forceinline__ float b2f(unsigned short u) {
  return __uint_as_float(((unsigned int)u) << 16);
}
static __device__ __forceinline__ unsigned char f2fp8(float f) {
  __hip_fp8_e4m3 t(f);          // OCP e4m3 on gfx950
  return (unsigned char)t.__x;
}

// ---------------------------------------------------------------------------
// K1: ep4[dir][v][col][gate] = bf16( dot(emb[v], Wih_dir[gate*256+col]) + biases )
// gate-last ushort4: one 8B load gives all 4 gate pre-activations.
// ---------------------------------------------------------------------------
__global__ __launch_bounds__(256) void k_embproj(
    const float* __restrict__ emb,
    const float* __restrict__ Wih_f, const float* __restrict__ bih_f, const float* __restrict__ bhh_f,
    const float* __restrict__ Wih_b, const float* __restrict__ bih_b, const float* __restrict__ bhh_b,
    unsigned short* __restrict__ ep4) {
  int v   = blockIdx.x & (V_ - 1);
  int dir = blockIdx.x >> 7;
  const float* Wih = dir ? Wih_b : Wih_f;
  const float* b1  = dir ? bih_b : bih_f;
  const float* b2  = dir ? bhh_b : bhh_f;
  __shared__ float es[E_];
  if (threadIdx.x < E_) es[threadIdx.x] = emb[v * E_ + threadIdx.x];
  __syncthreads();
#pragma unroll
  for (int q = 0; q < 4; ++q) {
    int g = q * 256 + threadIdx.x;       // g = gate*256 + col
    const float* wr = Wih + g * E_;
    float a = 0.f;
#pragma unroll 4
    for (int k = 0; k < E_; k += 4) {
      float4 w4 = *(const float4*)(wr + k);
      float4 e4 = *(const float4*)(es + k);
      a += w4.x * e4.x + w4.y * e4.y + w4.z * e4.z + w4.w * e4.w;
    }
    int gate = g >> 8, col = g & 255;
    union { __hip_bfloat16 b; unsigned short u; } cv;
    cv.b = __float2bfloat16(a + b1[g] + b2[g]);
    ep4[((((dir * V_ + v) << 8) + col) << 2) + gate] = cv.u;
  }
}

// ---------------------------------------------------------------------------
// K1b: pack Whh^T (256 x 1024) per dir into per-WAVE-contiguous fp8 MFMA
// B-fragment layout:  Bpack[dir][ks][w][f][lane][8 bytes]  (e4m3)
//   f = u*2 + jj -> nt = u*16 + 2*w + jj
//   elem j: Bmat[k][n] = Whh[n][k], k = ks*32 + (lane>>4)*8 + j,
//                                   n = nt*16 + (lane&15)
// Per (ks,w) a wave's 8 fragments are one contiguous 4KB chunk.
// ---------------------------------------------------------------------------
__global__ __launch_bounds__(64) void k_pack(
    const float* __restrict__ Whh_f, const float* __restrict__ Whh_b,
    unsigned char* __restrict__ Bpack) {
  const int lane = threadIdx.x;
  const int f    = blockIdx.x & 7;
  const int w    = (blockIdx.x >> 3) & 7;
  const int ks   = (blockIdx.x >> 6) % KS_;
  const int dir  = blockIdx.x / (64 * KS_);
  const float* Whh = dir ? Whh_b : Whh_f;
  const int u  = f >> 1, jj = f & 1;
  const int nt = u * 16 + 2 * w + jj;
  const int n  = nt * 16 + (lane & 15);
  const int k0 = ks * 32 + (lane >> 4) * 8;
  size_t base = ((((size_t)(dir * KS_ + ks) * 8 + w) * 8 + f) * 64 + lane) * 8;
#pragma unroll
  for (int j = 0; j < 8; ++j)
    Bpack[base + j] = f2fp8(Whh[n * H_ + k0 + j]);
}

// ---------------------------------------------------------------------------
// K1c: deterministic stable counting sort of words by length, DESCENDING.
// ---------------------------------------------------------------------------
#define NCHUNK 8
#define CHSZ  (NW / NCHUNK)
__global__ __launch_bounds__(256) void k_sort(const int* __restrict__ word_lens,
                                              int* __restrict__ perm) {
  __shared__ int cnt_s[NCHUNK][33];
  __shared__ int off_s[NCHUNK][33];
  const int tid = threadIdx.x;
  const int ch  = tid >> 5;
  const int ln  = (tid & 31) + 1;   // 1..32
  const int base = ch * CHSZ;
  int c = 0;
  for (int i = 0; i < CHSZ; ++i) c += (word_lens[base + i] == ln);
  cnt_s[ch][ln] = c;
  __syncthreads();
  if (tid == 0) {
    int run = 0;
    for (int l = 32; l >= 1; --l)
      for (int c2 = 0; c2 < NCHUNK; ++c2) { off_s[c2][l] = run; run += cnt_s[c2][l]; }
  }
  __syncthreads();
  int ptr = off_s[ch][ln];
  for (int i = 0; i < CHSZ; ++i) {
    int wi = base + i;
    if (word_lens[wi] == ln) perm[ptr++] = wi;
  }
}

// ---------------------------------------------------------------------------
// K2: fp8 MFMA BiLSTM recurrence. EXACT r8 skeleton (512 thr, 8 waves,
// M=32, two barriers, single hL, conditional h-write, gather-in-EW, LPT
// pairing) with bf16 -> fp8-e4m3 operands: panel 512KB -> 256KB/block-step.
// Wave w owns gate-cols {2w,2w+1}: nt = u*16 + x.  acc = 64 f32/thread.
// c-state f32; hr bf16 regs keep full output precision for hcat.
// C/D layout (verified m89): word = mt*16 + (lane>>4)*4 + r, col = lane&15.
// A/B fp8 frag: 8 bytes/lane, k = ks*32 + (lane>>4)*8 + j (same as bf16 map).
// ---------------------------------------------------------------------------
__global__ __launch_bounds__(512, 2) void k_lstm(
    const int* __restrict__ char_ids, const int* __restrict__ word_lens,
    const int* __restrict__ perm, const unsigned short* __restrict__ ep4,
    const unsigned char* __restrict__ Bpack, unsigned short* __restrict__ hcat) {
  const int tid  = threadIdx.x;
  const int lane = tid & 63;
  const int w    = tid >> 6;       // wave 0..7
  const int bid  = blockIdx.x;
  const int s    = (bid < 256) ? bid : 767 - bid;
  const int dir  = s & 1;
  const int w0   = (s >> 1) * M_;

  __shared__ unsigned char hL[M_][ROWB];   // 8.25 KB (fp8 h)
  __shared__ int ids_s[M_][L_ + 1];        // 4.2 KB
  __shared__ int len_s[M_];
  __shared__ int pw_s[M_];

  if (tid < M_) {
    int gw = perm[w0 + tid];
    pw_s[tid]  = gw;
    len_s[tid] = word_lens[gw];
  }
  __syncthreads();
  for (int i = tid; i < M_ * L_; i += 512) {
    int q = i >> 5;
    ids_s[q][i & 31] = char_ids[pw_s[q] * L_ + (i & 31)];
  }
  for (int i = tid; i < M_ * ROWB / 4; i += 512) ((unsigned int*)hL)[i] = 0u;
  __syncthreads();

  int mlen = 0;
#pragma unroll 8
  for (int m = 0; m < M_; ++m) mlen = max(mlen, len_s[m]);
  unsigned lrp[2];
#pragma unroll
  for (int mt = 0; mt < 2; ++mt) {
    int bw = mt * 16 + ((lane >> 4) << 2);
    lrp[mt] = (unsigned)len_s[bw] | ((unsigned)len_s[bw + 1] << 8) |
              ((unsigned)len_s[bw + 2] << 16) | ((unsigned)len_s[bw + 3] << 24);
  }

  // per-dir, per-wave B base: Bpack[dir][ks=0][w][0][lane][0]
  //   dir stride 256KB, w stride 4KB, lane stride 8B, ks stride 32KB,
  //   frag stride 512B.
  const char* Bb0 = (const char*)Bpack + (size_t)dir * (KS_ * 8 * 8 * 64 * 8)
                    + (size_t)w * (8 * 64 * 8) + (size_t)lane * 8;
  // A-frag base: frag(mt,ks) at ar + mt*16*ROWB + ks*32  (imm offsets)
  const char* ar = (const char*)&hL[lane & 15][0] + ((lane >> 4) << 3);
  const ushort4* epv = (const ushort4*)ep4 + ((size_t)dir << 15);  // dir*V*256
  const int p0 = 2 * w * 16 + (lane & 15);   // gather col of jj=0 (jj=1: +16)
  const int g4 = (lane >> 4) << 2;

  float c_[2][2][4];                         // [jj][mt][r]
  unsigned short hr[2][2][4];                // bf16 h (full precision out)
#pragma unroll
  for (int jj = 0; jj < 2; ++jj)
#pragma unroll
    for (int mt = 0; mt < 2; ++mt)
#pragma unroll
      for (int r = 0; r < 4; ++r) { c_[jj][mt][r] = 0.f; hr[jj][mt][r] = 0; }

  for (int t = 0; t < mlen; ++t) {
    // --- MFMA phase: reads hL (fp8) ---
    f4v acc[4][2][2];                        // [gate u][jj][mt]
#pragma unroll
    for (int u = 0; u < 4; ++u)
#pragma unroll
      for (int jj = 0; jj < 2; ++jj)
#pragma unroll
        for (int mt = 0; mt < 2; ++mt) acc[u][jj][mt] = (f4v){0.f, 0.f, 0.f, 0.f};

    const char* bp0 = Bb0;            // frags 0..3 (imm offs 0..1536)
    const char* bp1 = Bb0 + 2048;     // frags 4..7
#pragma unroll 2
    for (int ks = 0; ks < KS_; ++ks) {
      i64 af0 = *(const i64*)(ar + ks * 32);
      i64 af1 = *(const i64*)(ar + 16 * ROWB + ks * 32);
      i64 b0 = *(const i64*)(bp0 + 0);
      i64 b1 = *(const i64*)(bp0 + 512);
      i64 b2 = *(const i64*)(bp0 + 1024);
      i64 b3 = *(const i64*)(bp0 + 1536);
      i64 b4 = *(const i64*)(bp1 + 0);
      i64 b5 = *(const i64*)(bp1 + 512);
      i64 b6 = *(const i64*)(bp1 + 1024);
      i64 b7 = *(const i64*)(bp1 + 1536);
      acc[0][0][0] = __builtin_amdgcn_mfma_f32_16x16x32_fp8_fp8(af0, b0, acc[0][0][0], 0, 0, 0);
      acc[0][0][1] = __builtin_amdgcn_mfma_f32_16x16x32_fp8_fp8(af1, b0, acc[0][0][1], 0, 0, 0);
      acc[0][1][0] = __builtin_amdgcn_mfma_f32_16x16x32_fp8_fp8(af0, b1, acc[0][1][0], 0, 0, 0);
      acc[0][1][1] = __builtin_amdgcn_mfma_f32_16x16x32_fp8_fp8(af1, b1, acc[0][1][1], 0, 0, 0);
      acc[1][0][0] = __builtin_amdgcn_mfma_f32_16x16x32_fp8_fp8(af0, b2, acc[1][0][0], 0, 0, 0);
      acc[1][0][1] = __builtin_amdgcn_mfma_f32_16x16x32_fp8_fp8(af1, b2, acc[1][0][1], 0, 0, 0);
      acc[1][1][0] = __builtin_amdgcn_mfma_f32_16x16x32_fp8_fp8(af0, b3, acc[1][1][0], 0, 0, 0);
      acc[1][1][1] = __builtin_amdgcn_mfma_f32_16x16x32_fp8_fp8(af1, b3, acc[1][1][1], 0, 0, 0);
      acc[2][0][0] = __builtin_amdgcn_mfma_f32_16x16x32_fp8_fp8(af0, b4, acc[2][0][0], 0, 0, 0);
      acc[2][0][1] = __builtin_amdgcn_mfma_f32_16x16x32_fp8_fp8(af1, b4, acc[2][0][1], 0, 0, 0);
      acc[2][1][0] = __builtin_amdgcn_mfma_f32_16x16x32_fp8_fp8(af0, b5, acc[2][1][0], 0, 0, 0);
      acc[2][1][1] = __builtin_amdgcn_mfma_f32_16x16x32_fp8_fp8(af1, b5, acc[2][1][1], 0, 0, 0);
      acc[3][0][0] = __builtin_amdgcn_mfma_f32_16x16x32_fp8_fp8(af0, b6, acc[3][0][0], 0, 0, 0);
      acc[3][0][1] = __builtin_amdgcn_mfma_f32_16x16x32_fp8_fp8(af1, b6, acc[3][0][1], 0, 0, 0);
      acc[3][1][0] = __builtin_amdgcn_mfma_f32_16x16x32_fp8_fp8(af0, b7, acc[3][1][0], 0, 0, 0);
      acc[3][1][1] = __builtin_amdgcn_mfma_f32_16x16x32_fp8_fp8(af1, b7, acc[3][1][1], 0, 0, 0);
      bp0 += 32768;   // ks stride = 8w * 8f * 64lane * 8B
      bp1 += 32768;
    }

    __syncthreads();   // all waves done reading hL for step t

    // --- elementwise: gather ep4 (bf16), gates, conditional state update ---
    ushort4 xc0[2][4], xc1[2][4];            // [mt][r]
#pragma unroll
    for (int mt = 0; mt < 2; ++mt) {
#pragma unroll
      for (int r = 0; r < 4; ++r) {
        int len = (int)((lrp[mt] >> (8 * r)) & 255u);
        int tt  = dir ? max(len - 1 - t, 0) : t;   // t < mlen <= 32 in-bounds
        int id  = ids_s[mt * 16 + g4 + r][tt];
        xc0[mt][r] = epv[(id << 8) + p0];
        xc1[mt][r] = epv[(id << 8) + p0 + 16];
      }
    }
#pragma unroll
    for (int jj = 0; jj < 2; ++jj) {
#pragma unroll
      for (int mt = 0; mt < 2; ++mt) {
#pragma unroll
        for (int r = 0; r < 4; ++r) {
          ushort4 xw = jj ? xc1[mt][r] : xc0[mt][r];
          float gi = acc[0][jj][mt][r] + b2f(xw.x);
          float gf = acc[1][jj][mt][r] + b2f(xw.y);
          float gg = acc[2][jj][mt][r] + b2f(xw.z);
          float go = acc[3][jj][mt][r] + b2f(xw.w);
          float si = 1.f / (1.f + __expf(-gi));
          float sf = 1.f / (1.f + __expf(-gf));
          float so = 1.f / (1.f + __expf(-go));
          float tg = 2.f / (1.f + __expf(-2.f * gg)) - 1.f;
          float cn = sf * c_[jj][mt][r] + si * tg;
          float hn = so * (2.f / (1.f + __expf(-2.f * cn)) - 1.f);
          int  len = (int)((lrp[mt] >> (8 * r)) & 255u);
          if (t < len) {
            c_[jj][mt][r] = cn;
            union { __hip_bfloat16 b; unsigned short u; } cv;
            cv.b = __float2bfloat16(hn);
            hr[jj][mt][r] = cv.u;
            const int m = mt * 16 + g4 + r;
            const int p = (2 * w + jj) * 16 + (lane & 15);
            hL[m][p] = f2fp8(hn);
          }
        }
      }
    }
    __syncthreads();   // h(t+1) visible before next MFMA phase
  }

  // write frozen h (bf16, from regs) to hcat at ORIGINAL word position:
  // concat = [h_bwd | h_fwd]
  const int off = dir ? 0 : H_;
#pragma unroll
  for (int jj = 0; jj < 2; ++jj) {
#pragma unroll
    for (int mt = 0; mt < 2; ++mt) {
#pragma unroll
      for (int r = 0; r < 4; ++r) {
        int m = mt * 16 + g4 + r;
        int p = (2 * w + jj) * 16 + (lane & 15);
        hcat[(size_t)pw_s[m] * (2 * H_) + off + p] = hr[jj][mt][r];
      }
    }
  }
}

// ---------------------------------------------------------------------------
// K3: wemb = hcat(bf16) @ pW^T + pb;  also writes lens_out (= W) slots.
// ---------------------------------------------------------------------------
#define PM_ 16
__global__ __launch_bounds__(256) void k_proj(
    const unsigned short* __restrict__ hcat, const float* __restrict__ pW,
    const float* __restrict__ pb, float* __restrict__ out) {
  const int tid = threadIdx.x;
  const int n0  = blockIdx.x * PM_;
  __shared__ float hs[PM_][2 * H_];   // 32 KB
  for (int i = tid; i < PM_ * 2 * H_; i += 256) {
    unsigned int ui = ((unsigned int)hcat[(size_t)n0 * 2 * H_ + i]) << 16;
    ((float*)hs)[i] = __uint_as_float(ui);
  }
  __syncthreads();

  const float* pwr = pW + tid * (2 * H_);
  float acc[PM_];
#pragma unroll
  for (int m = 0; m < PM_; ++m) acc[m] = 0.f;

#pragma unroll 2
  for (int k = 0; k < 2 * H_; k += 4) {
    float4 w4 = *(const float4*)(pwr + k);
#pragma unroll
    for (int m = 0; m < PM_; ++m) {
      float4 h4 = *(const float4*)(&hs[m][k]);
      acc[m] += w4.x * h4.x + w4.y * h4.y + w4.z * h4.z + w4.w * h4.w;
    }
  }
  const float bias = pb[tid];
#pragma unroll
  for (int m = 0; m < PM_; ++m) out[(n0 + m) * H_ + tid] = acc[m] + bias;

  if (blockIdx.x == 0 && tid < B_) out[NW * H_ + tid] = (float)W_;
}

// ---------------------------------------------------------------------------
extern "C" void kernel_launch(void* const* d_in, const int* in_sizes, int n_in,
                              void* d_out, int out_size, void* d_ws, size_t ws_size,
                              hipStream_t stream) {
  const int*   char_ids  = (const int*)  d_in[0];
  const int*   word_lens = (const int*)  d_in[1];
  const float* emb       = (const float*)d_in[2];
  const float* Wih_f     = (const float*)d_in[3];
  const float* Whh_f     = (const float*)d_in[4];
  const float* bih_f     = (const float*)d_in[5];
  const float* bhh_f     = (const float*)d_in[6];
  const float* Wih_b     = (const float*)d_in[7];
  const float* Whh_b     = (const float*)d_in[8];
  const float* bih_b     = (const float*)d_in[9];
  const float* bhh_b     = (const float*)d_in[10];
  const float* pW        = (const float*)d_in[11];
  const float* pb        = (const float*)d_in[12];
  float* out = (float*)d_out;

  // ws layout: [Bpack(fp8) 512KB][ep4(bf16) 512KB][perm 32KB][hcat(bf16) 8.4MB]
  const size_t BPACK_BYTES = (size_t)2 * KS_ * 8 * 8 * 64 * 8;       // 512 KB
  const size_t EP4_BYTES   = (size_t)2 * V_ * 256 * 4 * 2;           // 512 KB
  unsigned char* Bpack = (unsigned char*)d_ws;
  unsigned short* ep4 = (unsigned short*)((char*)d_ws + BPACK_BYTES);
  int* perm = (int*)((char*)d_ws + BPACK_BYTES + EP4_BYTES);
  unsigned short* hcat = (unsigned short*)((char*)d_ws + BPACK_BYTES + EP4_BYTES + NW * sizeof(int));

  k_sort<<<dim3(1), dim3(256), 0, stream>>>(word_lens, perm);
  k_embproj<<<dim3(2 * V_), dim3(256), 0, stream>>>(emb, Wih_f, bih_f, bhh_f,
                                                    Wih_b, bih_b, bhh_b, ep4);
  k_pack<<<dim3(2 * KS_ * 64), dim3(64), 0, stream>>>(Whh_f, Whh_b, Bpack);
  k_lstm<<<dim3(512), dim3(512), 0, stream>>>(char_ids, word_lens, perm, ep4, Bpack, hcat);
  k_proj<<<dim3(NW / PM_), dim3(256), 0, stream>>>(hcat, pW, pb, out);
}

// Round 14
// 699.637 us; speedup vs baseline: 1.9284x; 1.0004x over previous
//
#include <hip/hip_runtime.h>
#include <hip/hip_bf16.h>
#include <hip/hip_fp8.h>
#include <math.h>

// Problem constants
#define B_  64
#define W_  128
#define L_  32
#define V_  128
#define E_  128
#define H_  256
#define G4_ 1024      // 4*H
#define NW  8192      // B*W words
#define KS_ 8         // MFMA k-steps: h only (K=256), K=32 per fp8 MFMA
#define ROWB 264      // hL row bytes: 256 fp8 + 8 pad (33*8, odd -> bank spread)
#define M_  32        // words per block

typedef long i64;
typedef short s8v  __attribute__((ext_vector_type(8)));
typedef float f4v  __attribute__((ext_vector_type(4)));

static __device__ __forceinline__ float b2f(unsigned short u) {
  return __uint_as_float(((unsigned int)u) << 16);
}
static __device__ __forceinline__ unsigned char f2fp8(float f) {
  __hip_fp8_e4m3 t(f);          // OCP e4m3 on gfx950
  return (unsigned char)t.__x;
}

// ---------------------------------------------------------------------------
// K1: ep4[dir][v][col][gate] = bf16( dot(emb[v], Wih_dir[gate*256+col]) + biases )
// gate-last ushort4: one 8B load gives all 4 gate pre-activations.
// ---------------------------------------------------------------------------
__global__ __launch_bounds__(256) void k_embproj(
    const float* __restrict__ emb,
    const float* __restrict__ Wih_f, const float* __restrict__ bih_f, const float* __restrict__ bhh_f,
    const float* __restrict__ Wih_b, const float* __restrict__ bih_b, const float* __restrict__ bhh_b,
    unsigned short* __restrict__ ep4) {
  int v   = blockIdx.x & (V_ - 1);
  int dir = blockIdx.x >> 7;
  const float* Wih = dir ? Wih_b : Wih_f;
  const float* b1  = dir ? bih_b : bih_f;
  const float* b2  = dir ? bhh_b : bhh_f;
  __shared__ float es[E_];
  if (threadIdx.x < E_) es[threadIdx.x] = emb[v * E_ + threadIdx.x];
  __syncthreads();
#pragma unroll
  for (int q = 0; q < 4; ++q) {
    int g = q * 256 + threadIdx.x;       // g = gate*256 + col
    const float* wr = Wih + g * E_;
    float a = 0.f;
#pragma unroll 4
    for (int k = 0; k < E_; k += 4) {
      float4 w4 = *(const float4*)(wr + k);
      float4 e4 = *(const float4*)(es + k);
      a += w4.x * e4.x + w4.y * e4.y + w4.z * e4.z + w4.w * e4.w;
    }
    int gate = g >> 8, col = g & 255;
    union { __hip_bfloat16 b; unsigned short u; } cv;
    cv.b = __float2bfloat16(a + b1[g] + b2[g]);
    ep4[((((dir * V_ + v) << 8) + col) << 2) + gate] = cv.u;
  }
}

// ---------------------------------------------------------------------------
// K1b: pack Whh^T (256 x 1024) per dir into per-WAVE-contiguous fp8 MFMA
// B-fragment layout:  Bpack[dir][ks][w][f][lane][8 bytes]  (e4m3)
//   f = u*2 + jj -> nt = u*16 + 2*w + jj
//   elem j: Bmat[k][n] = Whh[n][k], k = ks*32 + (lane>>4)*8 + j,
//                                   n = nt*16 + (lane&15)
// ---------------------------------------------------------------------------
__global__ __launch_bounds__(64) void k_pack(
    const float* __restrict__ Whh_f, const float* __restrict__ Whh_b,
    unsigned char* __restrict__ Bpack) {
  const int lane = threadIdx.x;
  const int f    = blockIdx.x & 7;
  const int w    = (blockIdx.x >> 3) & 7;
  const int ks   = (blockIdx.x >> 6) % KS_;
  const int dir  = blockIdx.x / (64 * KS_);
  const float* Whh = dir ? Whh_b : Whh_f;
  const int u  = f >> 1, jj = f & 1;
  const int nt = u * 16 + 2 * w + jj;
  const int n  = nt * 16 + (lane & 15);
  const int k0 = ks * 32 + (lane >> 4) * 8;
  size_t base = ((((size_t)(dir * KS_ + ks) * 8 + w) * 8 + f) * 64 + lane) * 8;
#pragma unroll
  for (int j = 0; j < 8; ++j)
    Bpack[base + j] = f2fp8(Whh[n * H_ + k0 + j]);
}

// ---------------------------------------------------------------------------
// K1c: deterministic stable counting sort of words by length, DESCENDING.
// ---------------------------------------------------------------------------
#define NCHUNK 8
#define CHSZ  (NW / NCHUNK)
__global__ __launch_bounds__(256) void k_sort(const int* __restrict__ word_lens,
                                              int* __restrict__ perm) {
  __shared__ int cnt_s[NCHUNK][33];
  __shared__ int off_s[NCHUNK][33];
  const int tid = threadIdx.x;
  const int ch  = tid >> 5;
  const int ln  = (tid & 31) + 1;   // 1..32
  const int base = ch * CHSZ;
  int c = 0;
  for (int i = 0; i < CHSZ; ++i) c += (word_lens[base + i] == ln);
  cnt_s[ch][ln] = c;
  __syncthreads();
  if (tid == 0) {
    int run = 0;
    for (int l = 32; l >= 1; --l)
      for (int c2 = 0; c2 < NCHUNK; ++c2) { off_s[c2][l] = run; run += cnt_s[c2][l]; }
  }
  __syncthreads();
  int ptr = off_s[ch][ln];
  for (int i = 0; i < CHSZ; ++i) {
    int wi = base + i;
    if (word_lens[wi] == ln) perm[ptr++] = wi;
  }
}

// ---------------------------------------------------------------------------
// K2: fp8 MFMA BiLSTM recurrence (r13 skeleton, 3 blocks/CU).
// Block = 32 sorted words x 1 dir, 8 waves; LPT pairing bid<256 ? bid : 767-bid.
// __launch_bounds__(512,3): VGPR cap ~84 (2nd arg = blocks/CU empirically);
// r13 measured 80 live -> fits; 6 waves/SIMD for cross-block overlap.
// Gather restructured per-mt (8 ushort4 transient instead of 16) to protect
// the register fit.  acc = 64 f32 (AGPR); c f32; hr bf16 for exact output.
// C/D layout (verified m89): word = mt*16 + (lane>>4)*4 + r, col = lane&15.
// ---------------------------------------------------------------------------
__global__ __launch_bounds__(512, 3) void k_lstm(
    const int* __restrict__ char_ids, const int* __restrict__ word_lens,
    const int* __restrict__ perm, const unsigned short* __restrict__ ep4,
    const unsigned char* __restrict__ Bpack, unsigned short* __restrict__ hcat) {
  const int tid  = threadIdx.x;
  const int lane = tid & 63;
  const int w    = tid >> 6;       // wave 0..7
  const int bid  = blockIdx.x;
  const int s    = (bid < 256) ? bid : 767 - bid;
  const int dir  = s & 1;
  const int w0   = (s >> 1) * M_;

  __shared__ unsigned char hL[M_][ROWB];   // 8.25 KB (fp8 h)
  __shared__ int ids_s[M_][L_ + 1];        // 4.2 KB
  __shared__ int len_s[M_];
  __shared__ int pw_s[M_];

  if (tid < M_) {
    int gw = perm[w0 + tid];
    pw_s[tid]  = gw;
    len_s[tid] = word_lens[gw];
  }
  __syncthreads();
  for (int i = tid; i < M_ * L_; i += 512) {
    int q = i >> 5;
    ids_s[q][i & 31] = char_ids[pw_s[q] * L_ + (i & 31)];
  }
  for (int i = tid; i < M_ * ROWB / 4; i += 512) ((unsigned int*)hL)[i] = 0u;
  __syncthreads();

  int mlen = 0;
#pragma unroll 8
  for (int m = 0; m < M_; ++m) mlen = max(mlen, len_s[m]);
  unsigned lrp[2];
#pragma unroll
  for (int mt = 0; mt < 2; ++mt) {
    int bw = mt * 16 + ((lane >> 4) << 2);
    lrp[mt] = (unsigned)len_s[bw] | ((unsigned)len_s[bw + 1] << 8) |
              ((unsigned)len_s[bw + 2] << 16) | ((unsigned)len_s[bw + 3] << 24);
  }

  // per-dir, per-wave B base: Bpack[dir][ks=0][w][0][lane][0]
  const char* Bb0 = (const char*)Bpack + (size_t)dir * (KS_ * 8 * 8 * 64 * 8)
                    + (size_t)w * (8 * 64 * 8) + (size_t)lane * 8;
  // A-frag base: frag(mt,ks) at ar + mt*16*ROWB + ks*32  (imm offsets)
  const char* ar = (const char*)&hL[lane & 15][0] + ((lane >> 4) << 3);
  const ushort4* epv = (const ushort4*)ep4 + ((size_t)dir << 15);  // dir*V*256
  const int p0 = 2 * w * 16 + (lane & 15);   // gather col of jj=0 (jj=1: +16)
  const int g4 = (lane >> 4) << 2;

  float c_[2][2][4];                         // [jj][mt][r]
  unsigned short hr[2][2][4];                // bf16 h (full precision out)
#pragma unroll
  for (int jj = 0; jj < 2; ++jj)
#pragma unroll
    for (int mt = 0; mt < 2; ++mt)
#pragma unroll
      for (int r = 0; r < 4; ++r) { c_[jj][mt][r] = 0.f; hr[jj][mt][r] = 0; }

  for (int t = 0; t < mlen; ++t) {
    // --- MFMA phase: reads hL (fp8) ---
    f4v acc[4][2][2];                        // [gate u][jj][mt]
#pragma unroll
    for (int u = 0; u < 4; ++u)
#pragma unroll
      for (int jj = 0; jj < 2; ++jj)
#pragma unroll
        for (int mt = 0; mt < 2; ++mt) acc[u][jj][mt] = (f4v){0.f, 0.f, 0.f, 0.f};

    const char* bp0 = Bb0;            // frags 0..3 (imm offs 0..1536)
    const char* bp1 = Bb0 + 2048;     // frags 4..7
#pragma unroll 2
    for (int ks = 0; ks < KS_; ++ks) {
      i64 af0 = *(const i64*)(ar + ks * 32);
      i64 af1 = *(const i64*)(ar + 16 * ROWB + ks * 32);
      i64 b0 = *(const i64*)(bp0 + 0);
      i64 b1 = *(const i64*)(bp0 + 512);
      i64 b2 = *(const i64*)(bp0 + 1024);
      i64 b3 = *(const i64*)(bp0 + 1536);
      i64 b4 = *(const i64*)(bp1 + 0);
      i64 b5 = *(const i64*)(bp1 + 512);
      i64 b6 = *(const i64*)(bp1 + 1024);
      i64 b7 = *(const i64*)(bp1 + 1536);
      acc[0][0][0] = __builtin_amdgcn_mfma_f32_16x16x32_fp8_fp8(af0, b0, acc[0][0][0], 0, 0, 0);
      acc[0][0][1] = __builtin_amdgcn_mfma_f32_16x16x32_fp8_fp8(af1, b0, acc[0][0][1], 0, 0, 0);
      acc[0][1][0] = __builtin_amdgcn_mfma_f32_16x16x32_fp8_fp8(af0, b1, acc[0][1][0], 0, 0, 0);
      acc[0][1][1] = __builtin_amdgcn_mfma_f32_16x16x32_fp8_fp8(af1, b1, acc[0][1][1], 0, 0, 0);
      acc[1][0][0] = __builtin_amdgcn_mfma_f32_16x16x32_fp8_fp8(af0, b2, acc[1][0][0], 0, 0, 0);
      acc[1][0][1] = __builtin_amdgcn_mfma_f32_16x16x32_fp8_fp8(af1, b2, acc[1][0][1], 0, 0, 0);
      acc[1][1][0] = __builtin_amdgcn_mfma_f32_16x16x32_fp8_fp8(af0, b3, acc[1][1][0], 0, 0, 0);
      acc[1][1][1] = __builtin_amdgcn_mfma_f32_16x16x32_fp8_fp8(af1, b3, acc[1][1][1], 0, 0, 0);
      acc[2][0][0] = __builtin_amdgcn_mfma_f32_16x16x32_fp8_fp8(af0, b4, acc[2][0][0], 0, 0, 0);
      acc[2][0][1] = __builtin_amdgcn_mfma_f32_16x16x32_fp8_fp8(af1, b4, acc[2][0][1], 0, 0, 0);
      acc[2][1][0] = __builtin_amdgcn_mfma_f32_16x16x32_fp8_fp8(af0, b5, acc[2][1][0], 0, 0, 0);
      acc[2][1][1] = __builtin_amdgcn_mfma_f32_16x16x32_fp8_fp8(af1, b5, acc[2][1][1], 0, 0, 0);
      acc[3][0][0] = __builtin_amdgcn_mfma_f32_16x16x32_fp8_fp8(af0, b6, acc[3][0][0], 0, 0, 0);
      acc[3][0][1] = __builtin_amdgcn_mfma_f32_16x16x32_fp8_fp8(af1, b6, acc[3][0][1], 0, 0, 0);
      acc[3][1][0] = __builtin_amdgcn_mfma_f32_16x16x32_fp8_fp8(af0, b7, acc[3][1][0], 0, 0, 0);
      acc[3][1][1] = __builtin_amdgcn_mfma_f32_16x16x32_fp8_fp8(af1, b7, acc[3][1][1], 0, 0, 0);
      bp0 += 32768;   // ks stride = 8w * 8f * 64lane * 8B
      bp1 += 32768;
    }

    __syncthreads();   // all waves done reading hL for step t

    // --- elementwise per mt: gather ep4 (8 ushort4 transient), gates,
    //     conditional state update ---
#pragma unroll
    for (int mt = 0; mt < 2; ++mt) {
      ushort4 xc0[4], xc1[4];
#pragma unroll
      for (int r = 0; r < 4; ++r) {
        int len = (int)((lrp[mt] >> (8 * r)) & 255u);
        int tt  = dir ? max(len - 1 - t, 0) : t;   // t < mlen <= 32 in-bounds
        int id  = ids_s[mt * 16 + g4 + r][tt];
        xc0[r] = epv[(id << 8) + p0];
        xc1[r] = epv[(id << 8) + p0 + 16];
      }
#pragma unroll
      for (int jj = 0; jj < 2; ++jj) {
#pragma unroll
        for (int r = 0; r < 4; ++r) {
          ushort4 xw = jj ? xc1[r] : xc0[r];
          float gi = acc[0][jj][mt][r] + b2f(xw.x);
          float gf = acc[1][jj][mt][r] + b2f(xw.y);
          float gg = acc[2][jj][mt][r] + b2f(xw.z);
          float go = acc[3][jj][mt][r] + b2f(xw.w);
          float si = 1.f / (1.f + __expf(-gi));
          float sf = 1.f / (1.f + __expf(-gf));
          float so = 1.f / (1.f + __expf(-go));
          float tg = 2.f / (1.f + __expf(-2.f * gg)) - 1.f;
          float cn = sf * c_[jj][mt][r] + si * tg;
          float hn = so * (2.f / (1.f + __expf(-2.f * cn)) - 1.f);
          int  len = (int)((lrp[mt] >> (8 * r)) & 255u);
          if (t < len) {
            c_[jj][mt][r] = cn;
            union { __hip_bfloat16 b; unsigned short u; } cv;
            cv.b = __float2bfloat16(hn);
            hr[jj][mt][r] = cv.u;
            const int m = mt * 16 + g4 + r;
            const int p = (2 * w + jj) * 16 + (lane & 15);
            hL[m][p] = f2fp8(hn);
          }
        }
      }
    }
    __syncthreads();   // h(t+1) visible before next MFMA phase
  }

  // write frozen h (bf16, from regs) to hcat at ORIGINAL word position:
  // concat = [h_bwd | h_fwd]
  const int off = dir ? 0 : H_;
#pragma unroll
  for (int jj = 0; jj < 2; ++jj) {
#pragma unroll
    for (int mt = 0; mt < 2; ++mt) {
#pragma unroll
      for (int r = 0; r < 4; ++r) {
        int m = mt * 16 + g4 + r;
        int p = (2 * w + jj) * 16 + (lane & 15);
        hcat[(size_t)pw_s[m] * (2 * H_) + off + p] = hr[jj][mt][r];
      }
    }
  }
}

// ---------------------------------------------------------------------------
// K3: wemb = hcat(bf16) @ pW^T + pb;  also writes lens_out (= W) slots.
// hcat loads vectorized 8-wide (bf16 scalar loads are 2-2.5x slower, G13).
// ---------------------------------------------------------------------------
#define PM_ 16
__global__ __launch_bounds__(256) void k_proj(
    const unsigned short* __restrict__ hcat, const float* __restrict__ pW,
    const float* __restrict__ pb, float* __restrict__ out) {
  const int tid = threadIdx.x;
  const int n0  = blockIdx.x * PM_;
  __shared__ float hs[PM_][2 * H_];   // 32 KB
  for (int i = tid; i < PM_ * 2 * H_ / 8; i += 256) {   // 1024 vec8, 4 iters
    s8v v = *(const s8v*)&hcat[(size_t)n0 * 2 * H_ + i * 8];
    float* d = (float*)hs + i * 8;
#pragma unroll
    for (int j = 0; j < 8; ++j) d[j] = b2f((unsigned short)v[j]);
  }
  __syncthreads();

  const float* pwr = pW + tid * (2 * H_);
  float acc[PM_];
#pragma unroll
  for (int m = 0; m < PM_; ++m) acc[m] = 0.f;

#pragma unroll 2
  for (int k = 0; k < 2 * H_; k += 4) {
    float4 w4 = *(const float4*)(pwr + k);
#pragma unroll
    for (int m = 0; m < PM_; ++m) {
      float4 h4 = *(const float4*)(&hs[m][k]);
      acc[m] += w4.x * h4.x + w4.y * h4.y + w4.z * h4.z + w4.w * h4.w;
    }
  }
  const float bias = pb[tid];
#pragma unroll
  for (int m = 0; m < PM_; ++m) out[(n0 + m) * H_ + tid] = acc[m] + bias;

  if (blockIdx.x == 0 && tid < B_) out[NW * H_ + tid] = (float)W_;
}

// ---------------------------------------------------------------------------
extern "C" void kernel_launch(void* const* d_in, const int* in_sizes, int n_in,
                              void* d_out, int out_size, void* d_ws, size_t ws_size,
                              hipStream_t stream) {
  const int*   char_ids  = (const int*)  d_in[0];
  const int*   word_lens = (const int*)  d_in[1];
  const float* emb       = (const float*)d_in[2];
  const float* Wih_f     = (const float*)d_in[3];
  const float* Whh_f     = (const float*)d_in[4];
  const float* bih_f     = (const float*)d_in[5];
  const float* bhh_f     = (const float*)d_in[6];
  const float* Wih_b     = (const float*)d_in[7];
  const float* Whh_b     = (const float*)d_in[8];
  const float* bih_b     = (const float*)d_in[9];
  const float* bhh_b     = (const float*)d_in[10];
  const float* pW        = (const float*)d_in[11];
  const float* pb        = (const float*)d_in[12];
  float* out = (float*)d_out;

  // ws layout: [Bpack(fp8) 512KB][ep4(bf16) 512KB][perm 32KB][hcat(bf16) 8.4MB]
  const size_t BPACK_BYTES = (size_t)2 * KS_ * 8 * 8 * 64 * 8;       // 512 KB
  const size_t EP4_BYTES   = (size_t)2 * V_ * 256 * 4 * 2;           // 512 KB
  unsigned char* Bpack = (unsigned char*)d_ws;
  unsigned short* ep4 = (unsigned short*)((char*)d_ws + BPACK_BYTES);
  int* perm = (int*)((char*)d_ws + BPACK_BYTES + EP4_BYTES);
  unsigned short* hcat = (unsigned short*)((char*)d_ws + BPACK_BYTES + EP4_BYTES + NW * sizeof(int));

  k_sort<<<dim3(1), dim3(256), 0, stream>>>(word_lens, perm);
  k_embproj<<<dim3(2 * V_), dim3(256), 0, stream>>>(emb, Wih_f, bih_f, bhh_f,
                                                    Wih_b, bih_b, bhh_b, ep4);
  k_pack<<<dim3(2 * KS_ * 64), dim3(64), 0, stream>>>(Whh_f, Whh_b, Bpack);
  k_lstm<<<dim3(512), dim3(512), 0, stream>>>(char_ids, word_lens, perm, ep4, Bpack, hcat);
  k_proj<<<dim3(NW / PM_), dim3(256), 0, stream>>>(hcat, pW, pb, out);
}

// Round 15
// 495.680 us; speedup vs baseline: 2.7218x; 1.4115x over previous
//
#include <hip/hip_runtime.h>
#include <hip/hip_bf16.h>
#include <hip/hip_fp8.h>
#include <math.h>

// Problem constants
#define B_  64
#define W_  128
#define L_  32
#define V_  128
#define E_  128
#define H_  256
#define G4_ 1024      // 4*H
#define NW  8192      // B*W words
#define KS_ 8         // MFMA k-steps: h only (K=256), K=32 per fp8 MFMA
#define ROWB 264      // hL row bytes: 256 fp8 + 8 pad
#define HROW 264      // hLb row (ushorts): 256 bf16 + 8 pad
#define M_  32        // words per block

typedef long i64;
typedef short s8v  __attribute__((ext_vector_type(8)));
typedef float f4v  __attribute__((ext_vector_type(4)));

static __device__ __forceinline__ float b2f(unsigned short u) {
  return __uint_as_float(((unsigned int)u) << 16);
}
static __device__ __forceinline__ unsigned char f2fp8(float f) {
  __hip_fp8_e4m3 t(f);          // OCP e4m3 on gfx950
  return (unsigned char)t.__x;
}

// ---------------------------------------------------------------------------
// K1: ep4[dir][v][col][gate] = bf16( dot(emb[v], Wih_dir[gate*256+col]) + biases )
// ---------------------------------------------------------------------------
__global__ __launch_bounds__(256) void k_embproj(
    const float* __restrict__ emb,
    const float* __restrict__ Wih_f, const float* __restrict__ bih_f, const float* __restrict__ bhh_f,
    const float* __restrict__ Wih_b, const float* __restrict__ bih_b, const float* __restrict__ bhh_b,
    unsigned short* __restrict__ ep4) {
  int v   = blockIdx.x & (V_ - 1);
  int dir = blockIdx.x >> 7;
  const float* Wih = dir ? Wih_b : Wih_f;
  const float* b1  = dir ? bih_b : bih_f;
  const float* b2  = dir ? bhh_b : bhh_f;
  __shared__ float es[E_];
  if (threadIdx.x < E_) es[threadIdx.x] = emb[v * E_ + threadIdx.x];
  __syncthreads();
#pragma unroll
  for (int q = 0; q < 4; ++q) {
    int g = q * 256 + threadIdx.x;       // g = gate*256 + col
    const float* wr = Wih + g * E_;
    float a = 0.f;
#pragma unroll 4
    for (int k = 0; k < E_; k += 4) {
      float4 w4 = *(const float4*)(wr + k);
      float4 e4 = *(const float4*)(es + k);
      a += w4.x * e4.x + w4.y * e4.y + w4.z * e4.z + w4.w * e4.w;
    }
    int gate = g >> 8, col = g & 255;
    union { __hip_bfloat16 b; unsigned short u; } cv;
    cv.b = __float2bfloat16(a + b1[g] + b2[g]);
    ep4[((((dir * V_ + v) << 8) + col) << 2) + gate] = cv.u;
  }
}

// ---------------------------------------------------------------------------
// K1b: pack Whh^T into per-WAVE-contiguous fp8 MFMA B-fragments:
// Bpack[dir][ks][w][f][lane][8B]  (e4m3);  f = u*2+jj -> nt = u*16+2w+jj
//   elem j: Whh[n][k], k = ks*32 + (lane>>4)*8 + j, n = nt*16 + (lane&15)
// ---------------------------------------------------------------------------
__global__ __launch_bounds__(64) void k_pack(
    const float* __restrict__ Whh_f, const float* __restrict__ Whh_b,
    unsigned char* __restrict__ Bpack) {
  const int lane = threadIdx.x;
  const int f    = blockIdx.x & 7;
  const int w    = (blockIdx.x >> 3) & 7;
  const int ks   = (blockIdx.x >> 6) % KS_;
  const int dir  = blockIdx.x / (64 * KS_);
  const float* Whh = dir ? Whh_b : Whh_f;
  const int u  = f >> 1, jj = f & 1;
  const int nt = u * 16 + 2 * w + jj;
  const int n  = nt * 16 + (lane & 15);
  const int k0 = ks * 32 + (lane >> 4) * 8;
  size_t base = ((((size_t)(dir * KS_ + ks) * 8 + w) * 8 + f) * 64 + lane) * 8;
#pragma unroll
  for (int j = 0; j < 8; ++j)
    Bpack[base + j] = f2fp8(Whh[n * H_ + k0 + j]);
}

// ---------------------------------------------------------------------------
// K1c: deterministic stable counting sort by length, DESCENDING.
// 1024 threads = 32 chunks x 32 length-values, 256 elems/thread (4x r13).
// ---------------------------------------------------------------------------
#define NCHUNK 32
#define CHSZ  (NW / NCHUNK)
__global__ __launch_bounds__(1024) void k_sort(const int* __restrict__ word_lens,
                                               int* __restrict__ perm) {
  __shared__ int cnt_s[NCHUNK][33];
  __shared__ int off_s[NCHUNK][33];
  const int tid = threadIdx.x;
  const int ch  = tid >> 5;
  const int ln  = (tid & 31) + 1;   // 1..32
  const int base = ch * CHSZ;
  int c = 0;
  for (int i = 0; i < CHSZ; ++i) c += (word_lens[base + i] == ln);
  cnt_s[ch][ln] = c;
  __syncthreads();
  if (tid == 0) {
    int run = 0;
    for (int l = 32; l >= 1; --l)
      for (int c2 = 0; c2 < NCHUNK; ++c2) { off_s[c2][l] = run; run += cnt_s[c2][l]; }
  }
  __syncthreads();
  int ptr = off_s[ch][ln];
  for (int i = 0; i < CHSZ; ++i) {
    int wi = base + i;
    if (word_lens[wi] == ln) perm[ptr++] = wi;
  }
}

// ---------------------------------------------------------------------------
// K2: fp8 MFMA BiLSTM recurrence — 2 RESIDENT BLOCKS/CU edition.
// r13 ran 1 block/CU: 72 arch + 64 AGPR = 136 regs > 128 -> 3 waves/SIMD.
// This round targets total <= 128: __launch_bounds__(512,4) (4 waves/EU),
// unroll-1 ks loop (B transients 32->16 regs), h bf16 evicted from regs to
// LDS hLb (-8 regs), mlen = len_s[0].
// Same-dir LPT pairing: quarters of bid -> CU c co-hosts two SAME-dir tasks
// (chunks c & 255-c), so both resident blocks stream the same 256KB panel.
// C/D layout (verified m89): word = mt*16 + (lane>>4)*4 + r, col = lane&15.
// ---------------------------------------------------------------------------
__global__ __launch_bounds__(512, 4) void k_lstm(
    const int* __restrict__ char_ids, const int* __restrict__ word_lens,
    const int* __restrict__ perm, const unsigned short* __restrict__ ep4,
    const unsigned char* __restrict__ Bpack, unsigned short* __restrict__ hcat) {
  const int tid  = threadIdx.x;
  const int lane = tid & 63;
  const int w    = tid >> 6;       // wave 0..7
  const int bid  = blockIdx.x;
  // quarter-based same-dir LPT: q0: (d0, bid), q1: (d1, bid-128),
  // q2: (d0, 511-bid), q3: (d1, 639-bid).  CU c gets bid c & c+256 (same dir).
  const int q    = bid >> 7;
  const int dir  = q & 1;
  const int chunk = (bid < 256) ? (bid & 127) : ((q == 2) ? 511 - bid : 639 - bid);
  const int w0   = chunk * M_;

  __shared__ unsigned char  hL [M_][ROWB];   // 8.25 KB (fp8 h, MFMA A operand)
  __shared__ unsigned short hLb[M_][HROW];   // 16.5 KB (bf16 h, output precision)
  __shared__ int ids_s[M_][L_ + 1];          // 4.2 KB
  __shared__ int len_s[M_];
  __shared__ int pw_s[M_];

  if (tid < M_) {
    int gw = perm[w0 + tid];
    pw_s[tid]  = gw;
    len_s[tid] = word_lens[gw];
  }
  __syncthreads();
  for (int i = tid; i < M_ * L_; i += 512) {
    int qq = i >> 5;
    ids_s[qq][i & 31] = char_ids[pw_s[qq] * L_ + (i & 31)];
  }
  for (int i = tid; i < M_ * ROWB / 4; i += 512) ((unsigned int*)hL)[i] = 0u;
  __syncthreads();

  const int mlen = len_s[0];   // descending sort -> first word in chunk is longest
  unsigned lrp[2];
#pragma unroll
  for (int mt = 0; mt < 2; ++mt) {
    int bw = mt * 16 + ((lane >> 4) << 2);
    lrp[mt] = (unsigned)len_s[bw] | ((unsigned)len_s[bw + 1] << 8) |
              ((unsigned)len_s[bw + 2] << 16) | ((unsigned)len_s[bw + 3] << 24);
  }

  // per-dir, per-wave B base: Bpack[dir][ks=0][w][0][lane][0]
  const char* Bb0 = (const char*)Bpack + (size_t)dir * (KS_ * 8 * 8 * 64 * 8)
                    + (size_t)w * (8 * 64 * 8) + (size_t)lane * 8;
  // A-frag base: frag(mt,ks) at ar + mt*16*ROWB + ks*32  (imm offsets)
  const char* ar = (const char*)&hL[lane & 15][0] + ((lane >> 4) << 3);
  const ushort4* epv = (const ushort4*)ep4 + ((size_t)dir << 15);  // dir*V*256
  const int p0 = 2 * w * 16 + (lane & 15);   // gather col of jj=0 (jj=1: +16)
  const int g4 = (lane >> 4) << 2;

  float c_[2][2][4];                         // [jj][mt][r]
#pragma unroll
  for (int jj = 0; jj < 2; ++jj)
#pragma unroll
    for (int mt = 0; mt < 2; ++mt)
#pragma unroll
      for (int r = 0; r < 4; ++r) c_[jj][mt][r] = 0.f;

  for (int t = 0; t < mlen; ++t) {
    // --- MFMA phase: reads hL (fp8) ---
    f4v acc[4][2][2];                        // [gate u][jj][mt]
#pragma unroll
    for (int u = 0; u < 4; ++u)
#pragma unroll
      for (int jj = 0; jj < 2; ++jj)
#pragma unroll
        for (int mt = 0; mt < 2; ++mt) acc[u][jj][mt] = (f4v){0.f, 0.f, 0.f, 0.f};

    const char* bp0 = Bb0;            // frags 0..3 (imm offs 0..1536)
    const char* bp1 = Bb0 + 2048;     // frags 4..7
#pragma unroll 1
    for (int ks = 0; ks < KS_; ++ks) {
      i64 af0 = *(const i64*)(ar + ks * 32);
      i64 af1 = *(const i64*)(ar + 16 * ROWB + ks * 32);
      i64 b0 = *(const i64*)(bp0 + 0);
      i64 b1 = *(const i64*)(bp0 + 512);
      i64 b2 = *(const i64*)(bp0 + 1024);
      i64 b3 = *(const i64*)(bp0 + 1536);
      i64 b4 = *(const i64*)(bp1 + 0);
      i64 b5 = *(const i64*)(bp1 + 512);
      i64 b6 = *(const i64*)(bp1 + 1024);
      i64 b7 = *(const i64*)(bp1 + 1536);
      acc[0][0][0] = __builtin_amdgcn_mfma_f32_16x16x32_fp8_fp8(af0, b0, acc[0][0][0], 0, 0, 0);
      acc[0][0][1] = __builtin_amdgcn_mfma_f32_16x16x32_fp8_fp8(af1, b0, acc[0][0][1], 0, 0, 0);
      acc[0][1][0] = __builtin_amdgcn_mfma_f32_16x16x32_fp8_fp8(af0, b1, acc[0][1][0], 0, 0, 0);
      acc[0][1][1] = __builtin_amdgcn_mfma_f32_16x16x32_fp8_fp8(af1, b1, acc[0][1][1], 0, 0, 0);
      acc[1][0][0] = __builtin_amdgcn_mfma_f32_16x16x32_fp8_fp8(af0, b2, acc[1][0][0], 0, 0, 0);
      acc[1][0][1] = __builtin_amdgcn_mfma_f32_16x16x32_fp8_fp8(af1, b2, acc[1][0][1], 0, 0, 0);
      acc[1][1][0] = __builtin_amdgcn_mfma_f32_16x16x32_fp8_fp8(af0, b3, acc[1][1][0], 0, 0, 0);
      acc[1][1][1] = __builtin_amdgcn_mfma_f32_16x16x32_fp8_fp8(af1, b3, acc[1][1][1], 0, 0, 0);
      acc[2][0][0] = __builtin_amdgcn_mfma_f32_16x16x32_fp8_fp8(af0, b4, acc[2][0][0], 0, 0, 0);
      acc[2][0][1] = __builtin_amdgcn_mfma_f32_16x16x32_fp8_fp8(af1, b4, acc[2][0][1], 0, 0, 0);
      acc[2][1][0] = __builtin_amdgcn_mfma_f32_16x16x32_fp8_fp8(af0, b5, acc[2][1][0], 0, 0, 0);
      acc[2][1][1] = __builtin_amdgcn_mfma_f32_16x16x32_fp8_fp8(af1, b5, acc[2][1][1], 0, 0, 0);
      acc[3][0][0] = __builtin_amdgcn_mfma_f32_16x16x32_fp8_fp8(af0, b6, acc[3][0][0], 0, 0, 0);
      acc[3][0][1] = __builtin_amdgcn_mfma_f32_16x16x32_fp8_fp8(af1, b6, acc[3][0][1], 0, 0, 0);
      acc[3][1][0] = __builtin_amdgcn_mfma_f32_16x16x32_fp8_fp8(af0, b7, acc[3][1][0], 0, 0, 0);
      acc[3][1][1] = __builtin_amdgcn_mfma_f32_16x16x32_fp8_fp8(af1, b7, acc[3][1][1], 0, 0, 0);
      bp0 += 32768;   // ks stride = 8w * 8f * 64lane * 8B
      bp1 += 32768;
    }

    __syncthreads();   // all waves done reading hL for step t

    // --- elementwise per mt: gather ep4, gates, conditional state update ---
#pragma unroll
    for (int mt = 0; mt < 2; ++mt) {
      ushort4 xc0[4], xc1[4];
#pragma unroll
      for (int r = 0; r < 4; ++r) {
        int len = (int)((lrp[mt] >> (8 * r)) & 255u);
        int tt  = dir ? max(len - 1 - t, 0) : t;   // t < mlen <= 32 in-bounds
        int id  = ids_s[mt * 16 + g4 + r][tt];
        xc0[r] = epv[(id << 8) + p0];
        xc1[r] = epv[(id << 8) + p0 + 16];
      }
#pragma unroll
      for (int jj = 0; jj < 2; ++jj) {
#pragma unroll
        for (int r = 0; r < 4; ++r) {
          ushort4 xw = jj ? xc1[r] : xc0[r];
          float gi = acc[0][jj][mt][r] + b2f(xw.x);
          float gf = acc[1][jj][mt][r] + b2f(xw.y);
          float gg = acc[2][jj][mt][r] + b2f(xw.z);
          float go = acc[3][jj][mt][r] + b2f(xw.w);
          float si = 1.f / (1.f + __expf(-gi));
          float sf = 1.f / (1.f + __expf(-gf));
          float so = 1.f / (1.f + __expf(-go));
          float tg = 2.f / (1.f + __expf(-2.f * gg)) - 1.f;
          float cn = sf * c_[jj][mt][r] + si * tg;
          float hn = so * (2.f / (1.f + __expf(-2.f * cn)) - 1.f);
          int  len = (int)((lrp[mt] >> (8 * r)) & 255u);
          if (t < len) {
            c_[jj][mt][r] = cn;
            union { __hip_bfloat16 b; unsigned short u; } cv;
            cv.b = __float2bfloat16(hn);
            const int m = mt * 16 + g4 + r;
            const int p = (2 * w + jj) * 16 + (lane & 15);
            hL [m][p] = f2fp8(hn);
            hLb[m][p] = cv.u;
          }
        }
      }
    }
    __syncthreads();   // h(t+1) visible before next MFMA phase
  }

  // write frozen h (bf16, from hLb) to hcat at ORIGINAL word position:
  // concat = [h_bwd | h_fwd]   (vectorized 8-wide; hLb fully written at t=0)
  const int off = dir ? 0 : H_;
  for (int i = tid; i < M_ * H_ / 8; i += 512) {   // 1024 vec8 chunks, 2 iters
    int qq  = i >> 5;              // local word
    int pos = (i & 31) << 3;       // col (multiple of 8)
    s8v v = *(const s8v*)&hLb[qq][pos];
    *(s8v*)&hcat[(size_t)pw_s[qq] * (2 * H_) + off + pos] = v;
  }
}

// ---------------------------------------------------------------------------
// K3: wemb = hcat(bf16) @ pW^T + pb;  also writes lens_out (= W) slots.
// ---------------------------------------------------------------------------
#define PM_ 16
__global__ __launch_bounds__(256) void k_proj(
    const unsigned short* __restrict__ hcat, const float* __restrict__ pW,
    const float* __restrict__ pb, float* __restrict__ out) {
  const int tid = threadIdx.x;
  const int n0  = blockIdx.x * PM_;
  __shared__ float hs[PM_][2 * H_];   // 32 KB
  for (int i = tid; i < PM_ * 2 * H_ / 8; i += 256) {   // 1024 vec8, 4 iters
    s8v v = *(const s8v*)&hcat[(size_t)n0 * 2 * H_ + i * 8];
    float* d = (float*)hs + i * 8;
#pragma unroll
    for (int j = 0; j < 8; ++j) d[j] = b2f((unsigned short)v[j]);
  }
  __syncthreads();

  const float* pwr = pW + tid * (2 * H_);
  float acc[PM_];
#pragma unroll
  for (int m = 0; m < PM_; ++m) acc[m] = 0.f;

#pragma unroll 2
  for (int k = 0; k < 2 * H_; k += 4) {
    float4 w4 = *(const float4*)(pwr + k);
#pragma unroll
    for (int m = 0; m < PM_; ++m) {
      float4 h4 = *(const float4*)(&hs[m][k]);
      acc[m] += w4.x * h4.x + w4.y * h4.y + w4.z * h4.z + w4.w * h4.w;
    }
  }
  const float bias = pb[tid];
#pragma unroll
  for (int m = 0; m < PM_; ++m) out[(n0 + m) * H_ + tid] = acc[m] + bias;

  if (blockIdx.x == 0 && tid < B_) out[NW * H_ + tid] = (float)W_;
}

// ---------------------------------------------------------------------------
extern "C" void kernel_launch(void* const* d_in, const int* in_sizes, int n_in,
                              void* d_out, int out_size, void* d_ws, size_t ws_size,
                              hipStream_t stream) {
  const int*   char_ids  = (const int*)  d_in[0];
  const int*   word_lens = (const int*)  d_in[1];
  const float* emb       = (const float*)d_in[2];
  const float* Wih_f     = (const float*)d_in[3];
  const float* Whh_f     = (const float*)d_in[4];
  const float* bih_f     = (const float*)d_in[5];
  const float* bhh_f     = (const float*)d_in[6];
  const float* Wih_b     = (const float*)d_in[7];
  const float* Whh_b     = (const float*)d_in[8];
  const float* bih_b     = (const float*)d_in[9];
  const float* bhh_b     = (const float*)d_in[10];
  const float* pW        = (const float*)d_in[11];
  const float* pb        = (const float*)d_in[12];
  float* out = (float*)d_out;

  // ws layout: [Bpack(fp8) 512KB][ep4(bf16) 512KB][perm 32KB][hcat(bf16) 8.4MB]
  const size_t BPACK_BYTES = (size_t)2 * KS_ * 8 * 8 * 64 * 8;       // 512 KB
  const size_t EP4_BYTES   = (size_t)2 * V_ * 256 * 4 * 2;           // 512 KB
  unsigned char* Bpack = (unsigned char*)d_ws;
  unsigned short* ep4 = (unsigned short*)((char*)d_ws + BPACK_BYTES);
  int* perm = (int*)((char*)d_ws + BPACK_BYTES + EP4_BYTES);
  unsigned short* hcat = (unsigned short*)((char*)d_ws + BPACK_BYTES + EP4_BYTES + NW * sizeof(int));

  k_sort<<<dim3(1), dim3(1024), 0, stream>>>(word_lens, perm);
  k_embproj<<<dim3(2 * V_), dim3(256), 0, stream>>>(emb, Wih_f, bih_f, bhh_f,
                                                    Wih_b, bih_b, bhh_b, ep4);
  k_pack<<<dim3(2 * KS_ * 64), dim3(64), 0, stream>>>(Whh_f, Whh_b, Bpack);
  k_lstm<<<dim3(512), dim3(512), 0, stream>>>(char_ids, word_lens, perm, ep4, Bpack, hcat);
  k_proj<<<dim3(NW / PM_), dim3(256), 0, stream>>>(hcat, pW, pb, out);
}

// Round 16
// 399.362 us; speedup vs baseline: 3.3783x; 1.2412x over previous
//
#include <hip/hip_runtime.h>
#include <hip/hip_bf16.h>
#include <hip/hip_fp8.h>
#include <math.h>

// Problem constants
#define B_  64
#define W_  128
#define L_  32
#define V_  128
#define E_  128
#define H_  256
#define G4_ 1024      // 4*H
#define NW  8192      // B*W words
#define KS_ 8         // MFMA k-steps: h only (K=256), K=32 per fp8 MFMA
#define ROWB 264      // hL row bytes: 256 fp8 + 8 pad
#define HROW 264      // hLb row (ushorts): 256 bf16 + 8 pad
#define M_  32        // words per block

typedef long i64;
typedef short s8v  __attribute__((ext_vector_type(8)));
typedef float f4v  __attribute__((ext_vector_type(4)));

static __device__ __forceinline__ float b2f(unsigned short u) {
  return __uint_as_float(((unsigned int)u) << 16);
}
static __device__ __forceinline__ unsigned char f2fp8(float f) {
  __hip_fp8_e4m3 t(f);          // OCP e4m3 on gfx950
  return (unsigned char)t.__x;
}
// fast sigmoid/tanh: v_exp + v_rcp (1-ulp) instead of precise IEEE division
// (each 1.f/x without fast-math expands to ~10-inst v_div_* sequence; the EW
// phase had 80 divisions/thread/step -> ~220us of VALU issue across rounds)
static __device__ __forceinline__ float sigm(float x) {
  return __builtin_amdgcn_rcpf(1.f + __expf(-x));
}
static __device__ __forceinline__ float tanh_(float x) {
  return __builtin_amdgcn_rcpf(1.f + __expf(-2.f * x)) * 2.f - 1.f;
}

// ---------------------------------------------------------------------------
// K1: ep4[dir][v][col][gate] = bf16( dot(emb[v], Wih_dir[gate*256+col]) + biases )
// ---------------------------------------------------------------------------
__global__ __launch_bounds__(256) void k_embproj(
    const float* __restrict__ emb,
    const float* __restrict__ Wih_f, const float* __restrict__ bih_f, const float* __restrict__ bhh_f,
    const float* __restrict__ Wih_b, const float* __restrict__ bih_b, const float* __restrict__ bhh_b,
    unsigned short* __restrict__ ep4) {
  int v   = blockIdx.x & (V_ - 1);
  int dir = blockIdx.x >> 7;
  const float* Wih = dir ? Wih_b : Wih_f;
  const float* b1  = dir ? bih_b : bih_f;
  const float* b2  = dir ? bhh_b : bhh_f;
  __shared__ float es[E_];
  if (threadIdx.x < E_) es[threadIdx.x] = emb[v * E_ + threadIdx.x];
  __syncthreads();
#pragma unroll
  for (int q = 0; q < 4; ++q) {
    int g = q * 256 + threadIdx.x;       // g = gate*256 + col
    const float* wr = Wih + g * E_;
    float a = 0.f;
#pragma unroll 4
    for (int k = 0; k < E_; k += 4) {
      float4 w4 = *(const float4*)(wr + k);
      float4 e4 = *(const float4*)(es + k);
      a += w4.x * e4.x + w4.y * e4.y + w4.z * e4.z + w4.w * e4.w;
    }
    int gate = g >> 8, col = g & 255;
    union { __hip_bfloat16 b; unsigned short u; } cv;
    cv.b = __float2bfloat16(a + b1[g] + b2[g]);
    ep4[((((dir * V_ + v) << 8) + col) << 2) + gate] = cv.u;
  }
}

// ---------------------------------------------------------------------------
// K1b: pack Whh^T into per-WAVE-contiguous fp8 MFMA B-fragments:
// Bpack[dir][ks][w][f][lane][8B]  (e4m3);  f = u*2+jj -> nt = u*16+2w+jj
//   elem j: Whh[n][k], k = ks*32 + (lane>>4)*8 + j, n = nt*16 + (lane&15)
// ---------------------------------------------------------------------------
__global__ __launch_bounds__(64) void k_pack(
    const float* __restrict__ Whh_f, const float* __restrict__ Whh_b,
    unsigned char* __restrict__ Bpack) {
  const int lane = threadIdx.x;
  const int f    = blockIdx.x & 7;
  const int w    = (blockIdx.x >> 3) & 7;
  const int ks   = (blockIdx.x >> 6) % KS_;
  const int dir  = blockIdx.x / (64 * KS_);
  const float* Whh = dir ? Whh_b : Whh_f;
  const int u  = f >> 1, jj = f & 1;
  const int nt = u * 16 + 2 * w + jj;
  const int n  = nt * 16 + (lane & 15);
  const int k0 = ks * 32 + (lane >> 4) * 8;
  size_t base = ((((size_t)(dir * KS_ + ks) * 8 + w) * 8 + f) * 64 + lane) * 8;
#pragma unroll
  for (int j = 0; j < 8; ++j)
    Bpack[base + j] = f2fp8(Whh[n * H_ + k0 + j]);
}

// ---------------------------------------------------------------------------
// K1c: deterministic stable counting sort by length, DESCENDING.
// ---------------------------------------------------------------------------
#define NCHUNK 32
#define CHSZ  (NW / NCHUNK)
__global__ __launch_bounds__(1024) void k_sort(const int* __restrict__ word_lens,
                                               int* __restrict__ perm) {
  __shared__ int cnt_s[NCHUNK][33];
  __shared__ int off_s[NCHUNK][33];
  const int tid = threadIdx.x;
  const int ch  = tid >> 5;
  const int ln  = (tid & 31) + 1;   // 1..32
  const int base = ch * CHSZ;
  int c = 0;
  for (int i = 0; i < CHSZ; ++i) c += (word_lens[base + i] == ln);
  cnt_s[ch][ln] = c;
  __syncthreads();
  if (tid == 0) {
    int run = 0;
    for (int l = 32; l >= 1; --l)
      for (int c2 = 0; c2 < NCHUNK; ++c2) { off_s[c2][l] = run; run += cnt_s[c2][l]; }
  }
  __syncthreads();
  int ptr = off_s[ch][ln];
  for (int i = 0; i < CHSZ; ++i) {
    int wi = base + i;
    if (word_lens[wi] == ln) perm[ptr++] = wi;
  }
}

// ---------------------------------------------------------------------------
// K2: fp8 MFMA BiLSTM recurrence — 2 resident blocks/CU (r15 geometry,
// UNCHANGED) + fast-transcendental EW.
// Block = 32 sorted words x 1 dir, 8 waves; quarter-based same-dir LPT.
// VGPR 64 arch + 64 AGPR acc = 128 -> 4 waves/SIMD (2 blocks).
// EW changes vs r15: sigm/tanh_ via v_rcp (no IEEE div expansion), hLb
// written only at the freeze step (t == len-1), act/fin masks hoisted.
// C/D layout (verified m89): word = mt*16 + (lane>>4)*4 + r, col = lane&15.
// ---------------------------------------------------------------------------
__global__ __launch_bounds__(512, 4) void k_lstm(
    const int* __restrict__ char_ids, const int* __restrict__ word_lens,
    const int* __restrict__ perm, const unsigned short* __restrict__ ep4,
    const unsigned char* __restrict__ Bpack, unsigned short* __restrict__ hcat) {
  const int tid  = threadIdx.x;
  const int lane = tid & 63;
  const int w    = tid >> 6;       // wave 0..7
  const int bid  = blockIdx.x;
  const int q    = bid >> 7;
  const int dir  = q & 1;
  const int chunk = (bid < 256) ? (bid & 127) : ((q == 2) ? 511 - bid : 639 - bid);
  const int w0   = chunk * M_;

  __shared__ unsigned char  hL [M_][ROWB];   // 8.25 KB (fp8 h, MFMA A operand)
  __shared__ unsigned short hLb[M_][HROW];   // 16.5 KB (bf16 h, output precision)
  __shared__ int ids_s[M_][L_ + 1];          // 4.2 KB
  __shared__ int len_s[M_];
  __shared__ int pw_s[M_];

  if (tid < M_) {
    int gw = perm[w0 + tid];
    pw_s[tid]  = gw;
    len_s[tid] = word_lens[gw];
  }
  __syncthreads();
  for (int i = tid; i < M_ * L_; i += 512) {
    int qq = i >> 5;
    ids_s[qq][i & 31] = char_ids[pw_s[qq] * L_ + (i & 31)];
  }
  for (int i = tid; i < M_ * ROWB / 4; i += 512) ((unsigned int*)hL)[i] = 0u;
  __syncthreads();

  const int mlen = len_s[0];   // descending sort -> first word in chunk is longest
  unsigned lrp[2];
#pragma unroll
  for (int mt = 0; mt < 2; ++mt) {
    int bw = mt * 16 + ((lane >> 4) << 2);
    lrp[mt] = (unsigned)len_s[bw] | ((unsigned)len_s[bw + 1] << 8) |
              ((unsigned)len_s[bw + 2] << 16) | ((unsigned)len_s[bw + 3] << 24);
  }

  // per-dir, per-wave B base: Bpack[dir][ks=0][w][0][lane][0]
  const char* Bb0 = (const char*)Bpack + (size_t)dir * (KS_ * 8 * 8 * 64 * 8)
                    + (size_t)w * (8 * 64 * 8) + (size_t)lane * 8;
  // A-frag base: frag(mt,ks) at ar + mt*16*ROWB + ks*32  (imm offsets)
  const char* ar = (const char*)&hL[lane & 15][0] + ((lane >> 4) << 3);
  const ushort4* epv = (const ushort4*)ep4 + ((size_t)dir << 15);  // dir*V*256
  const int p0 = 2 * w * 16 + (lane & 15);   // gather col of jj=0 (jj=1: +16)
  const int g4 = (lane >> 4) << 2;

  float c_[2][2][4];                         // [jj][mt][r]
#pragma unroll
  for (int jj = 0; jj < 2; ++jj)
#pragma unroll
    for (int mt = 0; mt < 2; ++mt)
#pragma unroll
      for (int r = 0; r < 4; ++r) c_[jj][mt][r] = 0.f;

  for (int t = 0; t < mlen; ++t) {
    // --- MFMA phase: reads hL (fp8) ---
    f4v acc[4][2][2];                        // [gate u][jj][mt]
#pragma unroll
    for (int u = 0; u < 4; ++u)
#pragma unroll
      for (int jj = 0; jj < 2; ++jj)
#pragma unroll
        for (int mt = 0; mt < 2; ++mt) acc[u][jj][mt] = (f4v){0.f, 0.f, 0.f, 0.f};

    const char* bp0 = Bb0;            // frags 0..3 (imm offs 0..1536)
    const char* bp1 = Bb0 + 2048;     // frags 4..7
#pragma unroll 1
    for (int ks = 0; ks < KS_; ++ks) {
      i64 af0 = *(const i64*)(ar + ks * 32);
      i64 af1 = *(const i64*)(ar + 16 * ROWB + ks * 32);
      i64 b0 = *(const i64*)(bp0 + 0);
      i64 b1 = *(const i64*)(bp0 + 512);
      i64 b2 = *(const i64*)(bp0 + 1024);
      i64 b3 = *(const i64*)(bp0 + 1536);
      i64 b4 = *(const i64*)(bp1 + 0);
      i64 b5 = *(const i64*)(bp1 + 512);
      i64 b6 = *(const i64*)(bp1 + 1024);
      i64 b7 = *(const i64*)(bp1 + 1536);
      acc[0][0][0] = __builtin_amdgcn_mfma_f32_16x16x32_fp8_fp8(af0, b0, acc[0][0][0], 0, 0, 0);
      acc[0][0][1] = __builtin_amdgcn_mfma_f32_16x16x32_fp8_fp8(af1, b0, acc[0][0][1], 0, 0, 0);
      acc[0][1][0] = __builtin_amdgcn_mfma_f32_16x16x32_fp8_fp8(af0, b1, acc[0][1][0], 0, 0, 0);
      acc[0][1][1] = __builtin_amdgcn_mfma_f32_16x16x32_fp8_fp8(af1, b1, acc[0][1][1], 0, 0, 0);
      acc[1][0][0] = __builtin_amdgcn_mfma_f32_16x16x32_fp8_fp8(af0, b2, acc[1][0][0], 0, 0, 0);
      acc[1][0][1] = __builtin_amdgcn_mfma_f32_16x16x32_fp8_fp8(af1, b2, acc[1][0][1], 0, 0, 0);
      acc[1][1][0] = __builtin_amdgcn_mfma_f32_16x16x32_fp8_fp8(af0, b3, acc[1][1][0], 0, 0, 0);
      acc[1][1][1] = __builtin_amdgcn_mfma_f32_16x16x32_fp8_fp8(af1, b3, acc[1][1][1], 0, 0, 0);
      acc[2][0][0] = __builtin_amdgcn_mfma_f32_16x16x32_fp8_fp8(af0, b4, acc[2][0][0], 0, 0, 0);
      acc[2][0][1] = __builtin_amdgcn_mfma_f32_16x16x32_fp8_fp8(af1, b4, acc[2][0][1], 0, 0, 0);
      acc[2][1][0] = __builtin_amdgcn_mfma_f32_16x16x32_fp8_fp8(af0, b5, acc[2][1][0], 0, 0, 0);
      acc[2][1][1] = __builtin_amdgcn_mfma_f32_16x16x32_fp8_fp8(af1, b5, acc[2][1][1], 0, 0, 0);
      acc[3][0][0] = __builtin_amdgcn_mfma_f32_16x16x32_fp8_fp8(af0, b6, acc[3][0][0], 0, 0, 0);
      acc[3][0][1] = __builtin_amdgcn_mfma_f32_16x16x32_fp8_fp8(af1, b6, acc[3][0][1], 0, 0, 0);
      acc[3][1][0] = __builtin_amdgcn_mfma_f32_16x16x32_fp8_fp8(af0, b7, acc[3][1][0], 0, 0, 0);
      acc[3][1][1] = __builtin_amdgcn_mfma_f32_16x16x32_fp8_fp8(af1, b7, acc[3][1][1], 0, 0, 0);
      bp0 += 32768;   // ks stride = 8w * 8f * 64lane * 8B
      bp1 += 32768;
    }

    __syncthreads();   // all waves done reading hL for step t

    // --- elementwise per mt: gather ep4, gates, conditional state update ---
#pragma unroll
    for (int mt = 0; mt < 2; ++mt) {
      ushort4 xc0[4], xc1[4];
      int act = 0, fin = 0;
#pragma unroll
      for (int r = 0; r < 4; ++r) {
        int len = (int)((lrp[mt] >> (8 * r)) & 255u);
        int tt  = dir ? max(len - 1 - t, 0) : t;   // t < mlen <= 32 in-bounds
        int id  = ids_s[mt * 16 + g4 + r][tt];
        xc0[r] = epv[(id << 8) + p0];
        xc1[r] = epv[(id << 8) + p0 + 16];
        act |= (t < len)      ? (1 << r) : 0;
        fin |= (t == len - 1) ? (1 << r) : 0;
      }
#pragma unroll
      for (int jj = 0; jj < 2; ++jj) {
#pragma unroll
        for (int r = 0; r < 4; ++r) {
          ushort4 xw = jj ? xc1[r] : xc0[r];
          float gi = acc[0][jj][mt][r] + b2f(xw.x);
          float gf = acc[1][jj][mt][r] + b2f(xw.y);
          float gg = acc[2][jj][mt][r] + b2f(xw.z);
          float go = acc[3][jj][mt][r] + b2f(xw.w);
          float cn = sigm(gf) * c_[jj][mt][r] + sigm(gi) * tanh_(gg);
          float hn = sigm(go) * tanh_(cn);
          const int m = mt * 16 + g4 + r;
          const int p = (2 * w + jj) * 16 + (lane & 15);
          if ((act >> r) & 1) {
            c_[jj][mt][r] = cn;
            hL[m][p] = f2fp8(hn);
          }
          if ((fin >> r) & 1) {
            union { __hip_bfloat16 b; unsigned short u; } cv;
            cv.b = __float2bfloat16(hn);
            hLb[m][p] = cv.u;
          }
        }
      }
    }
    __syncthreads();   // h(t+1) visible before next MFMA phase
  }

  // write frozen h (bf16, from hLb) to hcat at ORIGINAL word position:
  // concat = [h_bwd | h_fwd]   (each hLb elem written exactly once at freeze)
  const int off = dir ? 0 : H_;
  for (int i = tid; i < M_ * H_ / 8; i += 512) {   // 1024 vec8 chunks, 2 iters
    int qq  = i >> 5;              // local word
    int pos = (i & 31) << 3;       // col (multiple of 8)
    s8v v = *(const s8v*)&hLb[qq][pos];
    *(s8v*)&hcat[(size_t)pw_s[qq] * (2 * H_) + off + pos] = v;
  }
}

// ---------------------------------------------------------------------------
// K3: wemb = hcat(bf16) @ pW^T + pb;  also writes lens_out (= W) slots.
// ---------------------------------------------------------------------------
#define PM_ 16
__global__ __launch_bounds__(256) void k_proj(
    const unsigned short* __restrict__ hcat, const float* __restrict__ pW,
    const float* __restrict__ pb, float* __restrict__ out) {
  const int tid = threadIdx.x;
  const int n0  = blockIdx.x * PM_;
  __shared__ float hs[PM_][2 * H_];   // 32 KB
  for (int i = tid; i < PM_ * 2 * H_ / 8; i += 256) {   // 1024 vec8, 4 iters
    s8v v = *(const s8v*)&hcat[(size_t)n0 * 2 * H_ + i * 8];
    float* d = (float*)hs + i * 8;
#pragma unroll
    for (int j = 0; j < 8; ++j) d[j] = b2f((unsigned short)v[j]);
  }
  __syncthreads();

  const float* pwr = pW + tid * (2 * H_);
  float acc[PM_];
#pragma unroll
  for (int m = 0; m < PM_; ++m) acc[m] = 0.f;

#pragma unroll 2
  for (int k = 0; k < 2 * H_; k += 4) {
    float4 w4 = *(const float4*)(pwr + k);
#pragma unroll
    for (int m = 0; m < PM_; ++m) {
      float4 h4 = *(const float4*)(&hs[m][k]);
      acc[m] += w4.x * h4.x + w4.y * h4.y + w4.z * h4.z + w4.w * h4.w;
    }
  }
  const float bias = pb[tid];
#pragma unroll
  for (int m = 0; m < PM_; ++m) out[(n0 + m) * H_ + tid] = acc[m] + bias;

  if (blockIdx.x == 0 && tid < B_) out[NW * H_ + tid] = (float)W_;
}

// ---------------------------------------------------------------------------
extern "C" void kernel_launch(void* const* d_in, const int* in_sizes, int n_in,
                              void* d_out, int out_size, void* d_ws, size_t ws_size,
                              hipStream_t stream) {
  const int*   char_ids  = (const int*)  d_in[0];
  const int*   word_lens = (const int*)  d_in[1];
  const float* emb       = (const float*)d_in[2];
  const float* Wih_f     = (const float*)d_in[3];
  const float* Whh_f     = (const float*)d_in[4];
  const float* bih_f     = (const float*)d_in[5];
  const float* bhh_f     = (const float*)d_in[6];
  const float* Wih_b     = (const float*)d_in[7];
  const float* Whh_b     = (const float*)d_in[8];
  const float* bih_b     = (const float*)d_in[9];
  const float* bhh_b     = (const float*)d_in[10];
  const float* pW        = (const float*)d_in[11];
  const float* pb        = (const float*)d_in[12];
  float* out = (float*)d_out;

  // ws layout: [Bpack(fp8) 512KB][ep4(bf16) 512KB][perm 32KB][hcat(bf16) 8.4MB]
  const size_t BPACK_BYTES = (size_t)2 * KS_ * 8 * 8 * 64 * 8;       // 512 KB
  const size_t EP4_BYTES   = (size_t)2 * V_ * 256 * 4 * 2;           // 512 KB
  unsigned char* Bpack = (unsigned char*)d_ws;
  unsigned short* ep4 = (unsigned short*)((char*)d_ws + BPACK_BYTES);
  int* perm = (int*)((char*)d_ws + BPACK_BYTES + EP4_BYTES);
  unsigned short* hcat = (unsigned short*)((char*)d_ws + BPACK_BYTES + EP4_BYTES + NW * sizeof(int));

  k_sort<<<dim3(1), dim3(1024), 0, stream>>>(word_lens, perm);
  k_embproj<<<dim3(2 * V_), dim3(256), 0, stream>>>(emb, Wih_f, bih_f, bhh_f,
                                                    Wih_b, bih_b, bhh_b, ep4);
  k_pack<<<dim3(2 * KS_ * 64), dim3(64), 0, stream>>>(Whh_f, Whh_b, Bpack);
  k_lstm<<<dim3(512), dim3(512), 0, stream>>>(char_ids, word_lens, perm, ep4, Bpack, hcat);
  k_proj<<<dim3(NW / PM_), dim3(256), 0, stream>>>(hcat, pW, pb, out);
}

// Round 17
// 390.702 us; speedup vs baseline: 3.4532x; 1.0222x over previous
//
#include <hip/hip_runtime.h>
#include <hip/hip_bf16.h>
#include <hip/hip_fp8.h>
#include <math.h>

// Problem constants
#define B_  64
#define W_  128
#define L_  32
#define V_  128
#define E_  128
#define H_  256
#define G4_ 1024      // 4*H
#define NW  8192      // B*W words
#define KS_ 8         // MFMA k-steps: h only (K=256), K=32 per fp8 MFMA
#define ROWB 264      // hL row bytes: 256 fp8 + 8 pad
#define HROW 264      // hLb row (ushorts): 256 bf16 + 8 pad
#define M_  32        // words per block

typedef long i64;
typedef short s8v  __attribute__((ext_vector_type(8)));
typedef float f4v  __attribute__((ext_vector_type(4)));

static __device__ __forceinline__ float b2f(unsigned short u) {
  return __uint_as_float(((unsigned int)u) << 16);
}
static __device__ __forceinline__ unsigned char f2fp8(float f) {
  __hip_fp8_e4m3 t(f);          // OCP e4m3 on gfx950
  return (unsigned char)t.__x;
}
// fast sigmoid/tanh: v_exp + v_rcp (1-ulp), no IEEE div expansion
static __device__ __forceinline__ float sigm(float x) {
  return __builtin_amdgcn_rcpf(1.f + __expf(-x));
}
static __device__ __forceinline__ float tanh_(float x) {
  return __builtin_amdgcn_rcpf(1.f + __expf(-2.f * x)) * 2.f - 1.f;
}

// ---------------------------------------------------------------------------
// K_PREP: fused { embproj | sort | pack } — mutually independent, one launch.
//   blocks 0..255   : ep4[dir][v][col][gate] (1024 thr, one g per thread)
//   block  256      : counting sort by length, descending (stable)
//   blocks 257..320 : Whh^T -> fp8 B-fragment pack (16 tiles per block)
// ---------------------------------------------------------------------------
#define NCHUNK 32
#define CHSZ  (NW / NCHUNK)
__global__ __launch_bounds__(1024) void k_prep(
    const int* __restrict__ word_lens,
    const float* __restrict__ emb,
    const float* __restrict__ Wih_f, const float* __restrict__ bih_f, const float* __restrict__ bhh_f,
    const float* __restrict__ Wih_b, const float* __restrict__ bih_b, const float* __restrict__ bhh_b,
    const float* __restrict__ Whh_f, const float* __restrict__ Whh_b,
    unsigned short* __restrict__ ep4, int* __restrict__ perm,
    unsigned char* __restrict__ Bpack) {
  const int bb  = blockIdx.x;
  const int tid = threadIdx.x;

  if (bb < 256) {
    // ---- embproj: block = (dir, v); thread = g = gate*256 + col ----
    int v   = bb & (V_ - 1);
    int dir = bb >> 7;
    const float* Wih = dir ? Wih_b : Wih_f;
    const float* b1  = dir ? bih_b : bih_f;
    const float* b2  = dir ? bhh_b : bhh_f;
    __shared__ float es[E_];
    if (tid < E_) es[tid] = emb[v * E_ + tid];
    __syncthreads();
    const float* wr = Wih + tid * E_;
    float a = 0.f;
#pragma unroll 4
    for (int k = 0; k < E_; k += 4) {
      float4 w4 = *(const float4*)(wr + k);
      float4 e4 = *(const float4*)(es + k);
      a += w4.x * e4.x + w4.y * e4.y + w4.z * e4.z + w4.w * e4.w;
    }
    int gate = tid >> 8, col = tid & 255;
    union { __hip_bfloat16 b; unsigned short u; } cv;
    cv.b = __float2bfloat16(a + b1[tid] + b2[tid]);
    ep4[((((dir * V_ + v) << 8) + col) << 2) + gate] = cv.u;
  } else if (bb == 256) {
    // ---- counting sort, descending ----
    __shared__ int cnt_s[NCHUNK][33];
    __shared__ int off_s[NCHUNK][33];
    const int ch  = tid >> 5;
    const int ln  = (tid & 31) + 1;   // 1..32
    const int base = ch * CHSZ;
    int c = 0;
    for (int i = 0; i < CHSZ; ++i) c += (word_lens[base + i] == ln);
    cnt_s[ch][ln] = c;
    __syncthreads();
    if (tid == 0) {
      int run = 0;
      for (int l = 32; l >= 1; --l)
        for (int c2 = 0; c2 < NCHUNK; ++c2) { off_s[c2][l] = run; run += cnt_s[c2][l]; }
    }
    __syncthreads();
    int ptr = off_s[ch][ln];
    for (int i = 0; i < CHSZ; ++i) {
      int wi = base + i;
      if (word_lens[wi] == ln) perm[ptr++] = wi;
    }
  } else {
    // ---- pack: 64 blocks x 16 tiles; tile = (dir,ks,w,f), lane = tid&63 ----
    int tile = (bb - 257) * 16 + (tid >> 6);
    const int lane = tid & 63;
    const int f    = tile & 7;
    const int w    = (tile >> 3) & 7;
    const int ks   = (tile >> 6) % KS_;
    const int dir  = tile / (64 * KS_);
    const float* Whh = dir ? Whh_b : Whh_f;
    const int u  = f >> 1, jj = f & 1;
    const int nt = u * 16 + 2 * w + jj;
    const int n  = nt * 16 + (lane & 15);
    const int k0 = ks * 32 + (lane >> 4) * 8;
    size_t base = ((((size_t)(dir * KS_ + ks) * 8 + w) * 8 + f) * 64 + lane) * 8;
#pragma unroll
    for (int j = 0; j < 8; ++j)
      Bpack[base + j] = f2fp8(Whh[n * H_ + k0 + j]);
  }
}

// ---------------------------------------------------------------------------
// K2: fp8 MFMA BiLSTM recurrence — 2 resident blocks/CU, SINGLE barrier/step
// via double-buffered fp8 hL.  EW(t) writes buf[(t+1)&1] while MFMA(t) reads
// buf[t&1] (disjoint); the one barrier after EW orders EW(t) -> MFMA(t+1) and
// MFMA(t) -> EW(t+1) (program order + barrier).  Frozen words' stale A-rows
// are read but their gates are discarded by the act-mask -> harmless.
// Block = 32 sorted words x 1 dir, 8 waves; quarter-based same-dir LPT
// (CU c co-hosts same-dir chunks c & 255-c: shared Bpack panel in L1/L2).
// VGPR 64 arch + 64 AGPR acc = 128 -> 4 waves/SIMD (2 blocks).
// C/D layout (verified m89): word = mt*16 + (lane>>4)*4 + r, col = lane&15.
// ---------------------------------------------------------------------------
__global__ __launch_bounds__(512, 4) void k_lstm(
    const int* __restrict__ char_ids, const int* __restrict__ word_lens,
    const int* __restrict__ perm, const unsigned short* __restrict__ ep4,
    const unsigned char* __restrict__ Bpack, unsigned short* __restrict__ hcat) {
  const int tid  = threadIdx.x;
  const int lane = tid & 63;
  const int w    = tid >> 6;       // wave 0..7
  const int bid  = blockIdx.x;
  const int q    = bid >> 7;
  const int dir  = q & 1;
  const int chunk = (bid < 256) ? (bid & 127) : ((q == 2) ? 511 - bid : 639 - bid);
  const int w0   = chunk * M_;

  __shared__ unsigned char  hL[2][M_][ROWB];  // 16.5 KB (fp8 h, double buffer)
  __shared__ unsigned short hLb[M_][HROW];    // 16.5 KB (bf16 h at freeze)
  __shared__ int ids_s[M_][L_ + 1];           // 4.2 KB
  __shared__ int len_s[M_];
  __shared__ int pw_s[M_];

  if (tid < M_) {
    int gw = perm[w0 + tid];
    pw_s[tid]  = gw;
    len_s[tid] = word_lens[gw];
  }
  __syncthreads();
  for (int i = tid; i < M_ * L_; i += 512) {
    int qq = i >> 5;
    ids_s[qq][i & 31] = char_ids[pw_s[qq] * L_ + (i & 31)];
  }
  // zero buf0 only: buf1 is fully written by EW(0) (all words active at t=0)
  for (int i = tid; i < M_ * ROWB / 4; i += 512) ((unsigned int*)hL[0])[i] = 0u;
  __syncthreads();

  const int mlen = len_s[0];   // descending sort -> first word in chunk is longest
  unsigned lrp[2];
#pragma unroll
  for (int mt = 0; mt < 2; ++mt) {
    int bw = mt * 16 + ((lane >> 4) << 2);
    lrp[mt] = (unsigned)len_s[bw] | ((unsigned)len_s[bw + 1] << 8) |
              ((unsigned)len_s[bw + 2] << 16) | ((unsigned)len_s[bw + 3] << 24);
  }

  // per-dir, per-wave B base: Bpack[dir][ks=0][w][0][lane][0]
  const char* Bb0 = (const char*)Bpack + (size_t)dir * (KS_ * 8 * 8 * 64 * 8)
                    + (size_t)w * (8 * 64 * 8) + (size_t)lane * 8;
  // A-frag bases per buffer: frag(mt,ks) at ar + mt*16*ROWB + ks*32
  const char* arA = (const char*)&hL[0][lane & 15][0] + ((lane >> 4) << 3);
  const char* arB = arA + M_ * ROWB;
  unsigned char* hwA = &hL[0][0][0];          // EW(odd t) writes buf0
  unsigned char* hwB = &hL[1][0][0];          // EW(even t) writes buf1
  const ushort4* epv = (const ushort4*)ep4 + ((size_t)dir << 15);  // dir*V*256
  const int p0 = 2 * w * 16 + (lane & 15);   // gather col of jj=0 (jj=1: +16)
  const int g4 = (lane >> 4) << 2;

  float c_[2][2][4];                         // [jj][mt][r]
#pragma unroll
  for (int jj = 0; jj < 2; ++jj)
#pragma unroll
    for (int mt = 0; mt < 2; ++mt)
#pragma unroll
      for (int r = 0; r < 4; ++r) c_[jj][mt][r] = 0.f;

  for (int t = 0; t < mlen; ++t) {
    // --- MFMA phase: reads hL buf[t&1] (fp8) ---
    const char* ar = (t & 1) ? arB : arA;
    f4v acc[4][2][2];                        // [gate u][jj][mt]
#pragma unroll
    for (int u = 0; u < 4; ++u)
#pragma unroll
      for (int jj = 0; jj < 2; ++jj)
#pragma unroll
        for (int mt = 0; mt < 2; ++mt) acc[u][jj][mt] = (f4v){0.f, 0.f, 0.f, 0.f};

    const char* bp0 = Bb0;            // frags 0..3 (imm offs 0..1536)
    const char* bp1 = Bb0 + 2048;     // frags 4..7
#pragma unroll 1
    for (int ks = 0; ks < KS_; ++ks) {
      i64 af0 = *(const i64*)(ar + ks * 32);
      i64 af1 = *(const i64*)(ar + 16 * ROWB + ks * 32);
      i64 b0 = *(const i64*)(bp0 + 0);
      i64 b1 = *(const i64*)(bp0 + 512);
      i64 b2 = *(const i64*)(bp0 + 1024);
      i64 b3 = *(const i64*)(bp0 + 1536);
      i64 b4 = *(const i64*)(bp1 + 0);
      i64 b5 = *(const i64*)(bp1 + 512);
      i64 b6 = *(const i64*)(bp1 + 1024);
      i64 b7 = *(const i64*)(bp1 + 1536);
      acc[0][0][0] = __builtin_amdgcn_mfma_f32_16x16x32_fp8_fp8(af0, b0, acc[0][0][0], 0, 0, 0);
      acc[0][0][1] = __builtin_amdgcn_mfma_f32_16x16x32_fp8_fp8(af1, b0, acc[0][0][1], 0, 0, 0);
      acc[0][1][0] = __builtin_amdgcn_mfma_f32_16x16x32_fp8_fp8(af0, b1, acc[0][1][0], 0, 0, 0);
      acc[0][1][1] = __builtin_amdgcn_mfma_f32_16x16x32_fp8_fp8(af1, b1, acc[0][1][1], 0, 0, 0);
      acc[1][0][0] = __builtin_amdgcn_mfma_f32_16x16x32_fp8_fp8(af0, b2, acc[1][0][0], 0, 0, 0);
      acc[1][0][1] = __builtin_amdgcn_mfma_f32_16x16x32_fp8_fp8(af1, b2, acc[1][0][1], 0, 0, 0);
      acc[1][1][0] = __builtin_amdgcn_mfma_f32_16x16x32_fp8_fp8(af0, b3, acc[1][1][0], 0, 0, 0);
      acc[1][1][1] = __builtin_amdgcn_mfma_f32_16x16x32_fp8_fp8(af1, b3, acc[1][1][1], 0, 0, 0);
      acc[2][0][0] = __builtin_amdgcn_mfma_f32_16x16x32_fp8_fp8(af0, b4, acc[2][0][0], 0, 0, 0);
      acc[2][0][1] = __builtin_amdgcn_mfma_f32_16x16x32_fp8_fp8(af1, b4, acc[2][0][1], 0, 0, 0);
      acc[2][1][0] = __builtin_amdgcn_mfma_f32_16x16x32_fp8_fp8(af0, b5, acc[2][1][0], 0, 0, 0);
      acc[2][1][1] = __builtin_amdgcn_mfma_f32_16x16x32_fp8_fp8(af1, b5, acc[2][1][1], 0, 0, 0);
      acc[3][0][0] = __builtin_amdgcn_mfma_f32_16x16x32_fp8_fp8(af0, b6, acc[3][0][0], 0, 0, 0);
      acc[3][0][1] = __builtin_amdgcn_mfma_f32_16x16x32_fp8_fp8(af1, b6, acc[3][0][1], 0, 0, 0);
      acc[3][1][0] = __builtin_amdgcn_mfma_f32_16x16x32_fp8_fp8(af0, b7, acc[3][1][0], 0, 0, 0);
      acc[3][1][1] = __builtin_amdgcn_mfma_f32_16x16x32_fp8_fp8(af1, b7, acc[3][1][1], 0, 0, 0);
      bp0 += 32768;   // ks stride = 8w * 8f * 64lane * 8B
      bp1 += 32768;
    }

    // --- elementwise: gather ep4, gates, write h(t+1) to buf[(t+1)&1] ---
    unsigned char* hwb = (t & 1) ? hwA : hwB;
#pragma unroll
    for (int mt = 0; mt < 2; ++mt) {
      ushort4 xc0[4], xc1[4];
      int act = 0, fin = 0;
#pragma unroll
      for (int r = 0; r < 4; ++r) {
        int len = (int)((lrp[mt] >> (8 * r)) & 255u);
        int tt  = dir ? max(len - 1 - t, 0) : t;   // t < mlen <= 32 in-bounds
        int id  = ids_s[mt * 16 + g4 + r][tt];
        xc0[r] = epv[(id << 8) + p0];
        xc1[r] = epv[(id << 8) + p0 + 16];
        act |= (t < len)      ? (1 << r) : 0;
        fin |= (t == len - 1) ? (1 << r) : 0;
      }
#pragma unroll
      for (int jj = 0; jj < 2; ++jj) {
#pragma unroll
        for (int r = 0; r < 4; ++r) {
          ushort4 xw = jj ? xc1[r] : xc0[r];
          float gi = acc[0][jj][mt][r] + b2f(xw.x);
          float gf = acc[1][jj][mt][r] + b2f(xw.y);
          float gg = acc[2][jj][mt][r] + b2f(xw.z);
          float go = acc[3][jj][mt][r] + b2f(xw.w);
          float cn = sigm(gf) * c_[jj][mt][r] + sigm(gi) * tanh_(gg);
          float hn = sigm(go) * tanh_(cn);
          const int m = mt * 16 + g4 + r;
          const int p = (2 * w + jj) * 16 + (lane & 15);
          if ((act >> r) & 1) {
            c_[jj][mt][r] = cn;
            hwb[m * ROWB + p] = f2fp8(hn);
          }
          if ((fin >> r) & 1) {
            union { __hip_bfloat16 b; unsigned short u; } cv;
            cv.b = __float2bfloat16(hn);
            hLb[m][p] = cv.u;
          }
        }
      }
    }
    __syncthreads();   // EW(t) visible before MFMA(t+1); also orders
                       // MFMA(t) (pre-barrier) before EW(t+1) (post-barrier)
  }

  // write frozen h (bf16, from hLb) to hcat at ORIGINAL word position:
  // concat = [h_bwd | h_fwd]   (each hLb elem written exactly once at freeze)
  const int off = dir ? 0 : H_;
  for (int i = tid; i < M_ * H_ / 8; i += 512) {   // 1024 vec8 chunks, 2 iters
    int qq  = i >> 5;              // local word
    int pos = (i & 31) << 3;       // col (multiple of 8)
    s8v v = *(const s8v*)&hLb[qq][pos];
    *(s8v*)&hcat[(size_t)pw_s[qq] * (2 * H_) + off + pos] = v;
  }
}

// ---------------------------------------------------------------------------
// K3: wemb = hcat(bf16) @ pW^T + pb;  also writes lens_out (= W) slots.
// ---------------------------------------------------------------------------
#define PM_ 16
__global__ __launch_bounds__(256) void k_proj(
    const unsigned short* __restrict__ hcat, const float* __restrict__ pW,
    const float* __restrict__ pb, float* __restrict__ out) {
  const int tid = threadIdx.x;
  const int n0  = blockIdx.x * PM_;
  __shared__ float hs[PM_][2 * H_];   // 32 KB
  for (int i = tid; i < PM_ * 2 * H_ / 8; i += 256) {   // 1024 vec8, 4 iters
    s8v v = *(const s8v*)&hcat[(size_t)n0 * 2 * H_ + i * 8];
    float* d = (float*)hs + i * 8;
#pragma unroll
    for (int j = 0; j < 8; ++j) d[j] = b2f((unsigned short)v[j]);
  }
  __syncthreads();

  const float* pwr = pW + tid * (2 * H_);
  float acc[PM_];
#pragma unroll
  for (int m = 0; m < PM_; ++m) acc[m] = 0.f;

#pragma unroll 2
  for (int k = 0; k < 2 * H_; k += 4) {
    float4 w4 = *(const float4*)(pwr + k);
#pragma unroll
    for (int m = 0; m < PM_; ++m) {
      float4 h4 = *(const float4*)(&hs[m][k]);
      acc[m] += w4.x * h4.x + w4.y * h4.y + w4.z * h4.z + w4.w * h4.w;
    }
  }
  const float bias = pb[tid];
#pragma unroll
  for (int m = 0; m < PM_; ++m) out[(n0 + m) * H_ + tid] = acc[m] + bias;

  if (blockIdx.x == 0 && tid < B_) out[NW * H_ + tid] = (float)W_;
}

// ---------------------------------------------------------------------------
extern "C" void kernel_launch(void* const* d_in, const int* in_sizes, int n_in,
                              void* d_out, int out_size, void* d_ws, size_t ws_size,
                              hipStream_t stream) {
  const int*   char_ids  = (const int*)  d_in[0];
  const int*   word_lens = (const int*)  d_in[1];
  const float* emb       = (const float*)d_in[2];
  const float* Wih_f     = (const float*)d_in[3];
  const float* Whh_f     = (const float*)d_in[4];
  const float* bih_f     = (const float*)d_in[5];
  const float* bhh_f     = (const float*)d_in[6];
  const float* Wih_b     = (const float*)d_in[7];
  const float* Whh_b     = (const float*)d_in[8];
  const float* bih_b     = (const float*)d_in[9];
  const float* bhh_b     = (const float*)d_in[10];
  const float* pW        = (const float*)d_in[11];
  const float* pb        = (const float*)d_in[12];
  float* out = (float*)d_out;

  // ws layout: [Bpack(fp8) 512KB][ep4(bf16) 512KB][perm 32KB][hcat(bf16) 8.4MB]
  const size_t BPACK_BYTES = (size_t)2 * KS_ * 8 * 8 * 64 * 8;       // 512 KB
  const size_t EP4_BYTES   = (size_t)2 * V_ * 256 * 4 * 2;           // 512 KB
  unsigned char* Bpack = (unsigned char*)d_ws;
  unsigned short* ep4 = (unsigned short*)((char*)d_ws + BPACK_BYTES);
  int* perm = (int*)((char*)d_ws + BPACK_BYTES + EP4_BYTES);
  unsigned short* hcat = (unsigned short*)((char*)d_ws + BPACK_BYTES + EP4_BYTES + NW * sizeof(int));

  k_prep<<<dim3(321), dim3(1024), 0, stream>>>(word_lens, emb,
                                               Wih_f, bih_f, bhh_f,
                                               Wih_b, bih_b, bhh_b,
                                               Whh_f, Whh_b, ep4, perm, Bpack);
  k_lstm<<<dim3(512), dim3(512), 0, stream>>>(char_ids, word_lens, perm, ep4, Bpack, hcat);
  k_proj<<<dim3(NW / PM_), dim3(256), 0, stream>>>(hcat, pW, pb, out);
}

// Round 18
// 332.710 us; speedup vs baseline: 4.0551x; 1.1743x over previous
//
#include <hip/hip_runtime.h>
#include <hip/hip_bf16.h>
#include <hip/hip_fp8.h>
#include <math.h>

// Problem constants
#define B_  64
#define W_  128
#define L_  32
#define V_  128
#define E_  128
#define H_  256
#define G4_ 1024      // 4*H
#define NW  8192      // B*W words
#define KS_ 8         // MFMA k-steps: h only (K=256), K=32 per fp8 MFMA
#define ROWB 264      // hL row bytes: 256 fp8 + 8 pad
#define HROW 264      // hLb row (ushorts): 256 bf16 + 8 pad
#define M_  32        // words per block
#define PROW 520      // k_proj LDS row (ushorts): 512 + 8 pad (1040B, odd*16)

typedef long i64;
typedef short s8v  __attribute__((ext_vector_type(8)));
typedef float f4v  __attribute__((ext_vector_type(4)));

static __device__ __forceinline__ float b2f(unsigned short u) {
  return __uint_as_float(((unsigned int)u) << 16);
}
static __device__ __forceinline__ unsigned char f2fp8(float f) {
  __hip_fp8_e4m3 t(f);          // OCP e4m3 on gfx950
  return (unsigned char)t.__x;
}
static __device__ __forceinline__ unsigned short f2bfu(float f) {
  union { __hip_bfloat16 b; unsigned short u; } cv;
  cv.b = __float2bfloat16(f);
  return cv.u;
}
// fast sigmoid/tanh: v_exp + v_rcp (1-ulp), no IEEE div expansion
static __device__ __forceinline__ float sigm(float x) {
  return __builtin_amdgcn_rcpf(1.f + __expf(-x));
}
static __device__ __forceinline__ float tanh_(float x) {
  return __builtin_amdgcn_rcpf(1.f + __expf(-2.f * x)) * 2.f - 1.f;
}

// ---------------------------------------------------------------------------
// K_PREP: fused { embproj | sort | pack Whh | pack pW } — independent jobs.
//   blocks 0..255   : ep4[dir][v][col][gate] (1024 thr, one g per thread)
//   block  256      : counting sort by length, descending (stable)
//   blocks 257..320 : Whh^T -> fp8 B-fragment pack (16 tiles per block)
//   blocks 321..336 : pW -> bf16 B-fragment pack for k_proj (16 tiles/block)
// ---------------------------------------------------------------------------
#define NCHUNK 32
#define CHSZ  (NW / NCHUNK)
__global__ __launch_bounds__(1024) void k_prep(
    const int* __restrict__ word_lens,
    const float* __restrict__ emb,
    const float* __restrict__ Wih_f, const float* __restrict__ bih_f, const float* __restrict__ bhh_f,
    const float* __restrict__ Wih_b, const float* __restrict__ bih_b, const float* __restrict__ bhh_b,
    const float* __restrict__ Whh_f, const float* __restrict__ Whh_b,
    const float* __restrict__ pW,
    unsigned short* __restrict__ ep4, int* __restrict__ perm,
    unsigned char* __restrict__ Bpack, unsigned short* __restrict__ pWb) {
  const int bb  = blockIdx.x;
  const int tid = threadIdx.x;

  if (bb < 256) {
    // ---- embproj: block = (dir, v); thread = g = gate*256 + col ----
    int v   = bb & (V_ - 1);
    int dir = bb >> 7;
    const float* Wih = dir ? Wih_b : Wih_f;
    const float* b1  = dir ? bih_b : bih_f;
    const float* b2  = dir ? bhh_b : bhh_f;
    __shared__ float es[E_];
    if (tid < E_) es[tid] = emb[v * E_ + tid];
    __syncthreads();
    const float* wr = Wih + tid * E_;
    float a = 0.f;
#pragma unroll 4
    for (int k = 0; k < E_; k += 4) {
      float4 w4 = *(const float4*)(wr + k);
      float4 e4 = *(const float4*)(es + k);
      a += w4.x * e4.x + w4.y * e4.y + w4.z * e4.z + w4.w * e4.w;
    }
    int gate = tid >> 8, col = tid & 255;
    ep4[((((dir * V_ + v) << 8) + col) << 2) + gate] = f2bfu(a + b1[tid] + b2[tid]);
  } else if (bb == 256) {
    // ---- counting sort, descending ----
    __shared__ int cnt_s[NCHUNK][33];
    __shared__ int off_s[NCHUNK][33];
    const int ch  = tid >> 5;
    const int ln  = (tid & 31) + 1;   // 1..32
    const int base = ch * CHSZ;
    int c = 0;
    for (int i = 0; i < CHSZ; ++i) c += (word_lens[base + i] == ln);
    cnt_s[ch][ln] = c;
    __syncthreads();
    if (tid == 0) {
      int run = 0;
      for (int l = 32; l >= 1; --l)
        for (int c2 = 0; c2 < NCHUNK; ++c2) { off_s[c2][l] = run; run += cnt_s[c2][l]; }
    }
    __syncthreads();
    int ptr = off_s[ch][ln];
    for (int i = 0; i < CHSZ; ++i) {
      int wi = base + i;
      if (word_lens[wi] == ln) perm[ptr++] = wi;
    }
  } else if (bb <= 320) {
    // ---- Whh pack: 64 blocks x 16 tiles; tile = (dir,ks,w,f) ----
    int tile = (bb - 257) * 16 + (tid >> 6);
    const int lane = tid & 63;
    const int f    = tile & 7;
    const int w    = (tile >> 3) & 7;
    const int ks   = (tile >> 6) % KS_;
    const int dir  = tile / (64 * KS_);
    const float* Whh = dir ? Whh_b : Whh_f;
    const int u  = f >> 1, jj = f & 1;
    const int nt = u * 16 + 2 * w + jj;
    const int n  = nt * 16 + (lane & 15);
    const int k0 = ks * 32 + (lane >> 4) * 8;
    size_t base = ((((size_t)(dir * KS_ + ks) * 8 + w) * 8 + f) * 64 + lane) * 8;
#pragma unroll
    for (int j = 0; j < 8; ++j)
      Bpack[base + j] = f2fp8(Whh[n * H_ + k0 + j]);
  } else {
    // ---- pW pack (bf16): 16 blocks x 16 tiles; tile tp = ks*16 + nt ----
    // pWb[ks(16)][w(8)][f(2)][lane][8]; nt = w*2+f; elem j: pW[n][k],
    //   k = ks*32 + (lane>>4)*8 + j, n = nt*16 + (lane&15)
    int tp = (bb - 321) * 16 + (tid >> 6);
    const int lane = tid & 63;
    const int ks = tp >> 4;
    const int nt = tp & 15;
    const int w  = nt >> 1, f = nt & 1;
    const int n  = nt * 16 + (lane & 15);
    const int k0 = ks * 32 + (lane >> 4) * 8;
    size_t base = ((((size_t)ks * 8 + w) * 2 + f) * 64 + lane) * 8;
#pragma unroll
    for (int j = 0; j < 8; ++j)
      pWb[base + j] = f2bfu(pW[n * (2 * H_) + k0 + j]);
  }
}

// ---------------------------------------------------------------------------
// K2: fp8 MFMA BiLSTM recurrence — UNCHANGED from r17 (proven: 278us,
// VGPR 64 + 64 AGPR = 128, 2 blocks/CU, single barrier, fp8 dbuf hL).
// ---------------------------------------------------------------------------
__global__ __launch_bounds__(512, 4) void k_lstm(
    const int* __restrict__ char_ids, const int* __restrict__ word_lens,
    const int* __restrict__ perm, const unsigned short* __restrict__ ep4,
    const unsigned char* __restrict__ Bpack, unsigned short* __restrict__ hcat) {
  const int tid  = threadIdx.x;
  const int lane = tid & 63;
  const int w    = tid >> 6;       // wave 0..7
  const int bid  = blockIdx.x;
  const int q    = bid >> 7;
  const int dir  = q & 1;
  const int chunk = (bid < 256) ? (bid & 127) : ((q == 2) ? 511 - bid : 639 - bid);
  const int w0   = chunk * M_;

  __shared__ unsigned char  hL[2][M_][ROWB];  // 16.5 KB (fp8 h, double buffer)
  __shared__ unsigned short hLb[M_][HROW];    // 16.5 KB (bf16 h at freeze)
  __shared__ int ids_s[M_][L_ + 1];           // 4.2 KB
  __shared__ int len_s[M_];
  __shared__ int pw_s[M_];

  if (tid < M_) {
    int gw = perm[w0 + tid];
    pw_s[tid]  = gw;
    len_s[tid] = word_lens[gw];
  }
  __syncthreads();
  for (int i = tid; i < M_ * L_; i += 512) {
    int qq = i >> 5;
    ids_s[qq][i & 31] = char_ids[pw_s[qq] * L_ + (i & 31)];
  }
  for (int i = tid; i < M_ * ROWB / 4; i += 512) ((unsigned int*)hL[0])[i] = 0u;
  __syncthreads();

  const int mlen = len_s[0];   // descending sort -> first word is longest
  unsigned lrp[2];
#pragma unroll
  for (int mt = 0; mt < 2; ++mt) {
    int bw = mt * 16 + ((lane >> 4) << 2);
    lrp[mt] = (unsigned)len_s[bw] | ((unsigned)len_s[bw + 1] << 8) |
              ((unsigned)len_s[bw + 2] << 16) | ((unsigned)len_s[bw + 3] << 24);
  }

  const char* Bb0 = (const char*)Bpack + (size_t)dir * (KS_ * 8 * 8 * 64 * 8)
                    + (size_t)w * (8 * 64 * 8) + (size_t)lane * 8;
  const char* arA = (const char*)&hL[0][lane & 15][0] + ((lane >> 4) << 3);
  const char* arB = arA + M_ * ROWB;
  unsigned char* hwA = &hL[0][0][0];
  unsigned char* hwB = &hL[1][0][0];
  const ushort4* epv = (const ushort4*)ep4 + ((size_t)dir << 15);
  const int p0 = 2 * w * 16 + (lane & 15);
  const int g4 = (lane >> 4) << 2;

  float c_[2][2][4];
#pragma unroll
  for (int jj = 0; jj < 2; ++jj)
#pragma unroll
    for (int mt = 0; mt < 2; ++mt)
#pragma unroll
      for (int r = 0; r < 4; ++r) c_[jj][mt][r] = 0.f;

  for (int t = 0; t < mlen; ++t) {
    const char* ar = (t & 1) ? arB : arA;
    f4v acc[4][2][2];
#pragma unroll
    for (int u = 0; u < 4; ++u)
#pragma unroll
      for (int jj = 0; jj < 2; ++jj)
#pragma unroll
        for (int mt = 0; mt < 2; ++mt) acc[u][jj][mt] = (f4v){0.f, 0.f, 0.f, 0.f};

    const char* bp0 = Bb0;
    const char* bp1 = Bb0 + 2048;
#pragma unroll 1
    for (int ks = 0; ks < KS_; ++ks) {
      i64 af0 = *(const i64*)(ar + ks * 32);
      i64 af1 = *(const i64*)(ar + 16 * ROWB + ks * 32);
      i64 b0 = *(const i64*)(bp0 + 0);
      i64 b1 = *(const i64*)(bp0 + 512);
      i64 b2 = *(const i64*)(bp0 + 1024);
      i64 b3 = *(const i64*)(bp0 + 1536);
      i64 b4 = *(const i64*)(bp1 + 0);
      i64 b5 = *(const i64*)(bp1 + 512);
      i64 b6 = *(const i64*)(bp1 + 1024);
      i64 b7 = *(const i64*)(bp1 + 1536);
      acc[0][0][0] = __builtin_amdgcn_mfma_f32_16x16x32_fp8_fp8(af0, b0, acc[0][0][0], 0, 0, 0);
      acc[0][0][1] = __builtin_amdgcn_mfma_f32_16x16x32_fp8_fp8(af1, b0, acc[0][0][1], 0, 0, 0);
      acc[0][1][0] = __builtin_amdgcn_mfma_f32_16x16x32_fp8_fp8(af0, b1, acc[0][1][0], 0, 0, 0);
      acc[0][1][1] = __builtin_amdgcn_mfma_f32_16x16x32_fp8_fp8(af1, b1, acc[0][1][1], 0, 0, 0);
      acc[1][0][0] = __builtin_amdgcn_mfma_f32_16x16x32_fp8_fp8(af0, b2, acc[1][0][0], 0, 0, 0);
      acc[1][0][1] = __builtin_amdgcn_mfma_f32_16x16x32_fp8_fp8(af1, b2, acc[1][0][1], 0, 0, 0);
      acc[1][1][0] = __builtin_amdgcn_mfma_f32_16x16x32_fp8_fp8(af0, b3, acc[1][1][0], 0, 0, 0);
      acc[1][1][1] = __builtin_amdgcn_mfma_f32_16x16x32_fp8_fp8(af1, b3, acc[1][1][1], 0, 0, 0);
      acc[2][0][0] = __builtin_amdgcn_mfma_f32_16x16x32_fp8_fp8(af0, b4, acc[2][0][0], 0, 0, 0);
      acc[2][0][1] = __builtin_amdgcn_mfma_f32_16x16x32_fp8_fp8(af1, b4, acc[2][0][1], 0, 0, 0);
      acc[2][1][0] = __builtin_amdgcn_mfma_f32_16x16x32_fp8_fp8(af0, b5, acc[2][1][0], 0, 0, 0);
      acc[2][1][1] = __builtin_amdgcn_mfma_f32_16x16x32_fp8_fp8(af1, b5, acc[2][1][1], 0, 0, 0);
      acc[3][0][0] = __builtin_amdgcn_mfma_f32_16x16x32_fp8_fp8(af0, b6, acc[3][0][0], 0, 0, 0);
      acc[3][0][1] = __builtin_amdgcn_mfma_f32_16x16x32_fp8_fp8(af1, b6, acc[3][0][1], 0, 0, 0);
      acc[3][1][0] = __builtin_amdgcn_mfma_f32_16x16x32_fp8_fp8(af0, b7, acc[3][1][0], 0, 0, 0);
      acc[3][1][1] = __builtin_amdgcn_mfma_f32_16x16x32_fp8_fp8(af1, b7, acc[3][1][1], 0, 0, 0);
      bp0 += 32768;
      bp1 += 32768;
    }

    unsigned char* hwb = (t & 1) ? hwA : hwB;
#pragma unroll
    for (int mt = 0; mt < 2; ++mt) {
      ushort4 xc0[4], xc1[4];
      int act = 0, fin = 0;
#pragma unroll
      for (int r = 0; r < 4; ++r) {
        int len = (int)((lrp[mt] >> (8 * r)) & 255u);
        int tt  = dir ? max(len - 1 - t, 0) : t;
        int id  = ids_s[mt * 16 + g4 + r][tt];
        xc0[r] = epv[(id << 8) + p0];
        xc1[r] = epv[(id << 8) + p0 + 16];
        act |= (t < len)      ? (1 << r) : 0;
        fin |= (t == len - 1) ? (1 << r) : 0;
      }
#pragma unroll
      for (int jj = 0; jj < 2; ++jj) {
#pragma unroll
        for (int r = 0; r < 4; ++r) {
          ushort4 xw = jj ? xc1[r] : xc0[r];
          float gi = acc[0][jj][mt][r] + b2f(xw.x);
          float gf = acc[1][jj][mt][r] + b2f(xw.y);
          float gg = acc[2][jj][mt][r] + b2f(xw.z);
          float go = acc[3][jj][mt][r] + b2f(xw.w);
          float cn = sigm(gf) * c_[jj][mt][r] + sigm(gi) * tanh_(gg);
          float hn = sigm(go) * tanh_(cn);
          const int m = mt * 16 + g4 + r;
          const int p = (2 * w + jj) * 16 + (lane & 15);
          if ((act >> r) & 1) {
            c_[jj][mt][r] = cn;
            hwb[m * ROWB + p] = f2fp8(hn);
          }
          if ((fin >> r) & 1) hLb[m][p] = f2bfu(hn);
        }
      }
    }
    __syncthreads();
  }

  const int off = dir ? 0 : H_;
  for (int i = tid; i < M_ * H_ / 8; i += 512) {
    int qq  = i >> 5;
    int pos = (i & 31) << 3;
    s8v v = *(const s8v*)&hLb[qq][pos];
    *(s8v*)&hcat[(size_t)pw_s[qq] * (2 * H_) + off + pos] = v;
  }
}

// ---------------------------------------------------------------------------
// K3: wemb = hcat(bf16) @ pW^T + pb via bf16 MFMA.  Block = 32 words, 8 waves.
// Wave w owns col-tiles nt in {2w, 2w+1}; 16 k-steps; acc = 16 f32/thread.
// hcat tile staged in LDS with row stride 520 ushorts (1040B, odd*16 ->
// balanced bank quads).  C/D (m89): row = mt*16+(lane>>4)*4+reg, col=lane&15.
// Also writes lens_out (= W) slots.
// ---------------------------------------------------------------------------
__global__ __launch_bounds__(512) void k_proj(
    const unsigned short* __restrict__ hcat, const unsigned short* __restrict__ pWb,
    const float* __restrict__ pb, float* __restrict__ out) {
  const int tid  = threadIdx.x;
  const int lane = tid & 63;
  const int w    = tid >> 6;
  const int n0   = blockIdx.x * 32;

  __shared__ unsigned short hs[32][PROW];   // 33.3 KB
  for (int i = tid; i < 32 * (2 * H_) / 8; i += 512) {  // 2048 vec8, 4 iters
    int qq  = i >> 6;               // word 0..31
    int pos = (i & 63) << 3;        // col (multiple of 8)
    *(s8v*)&hs[qq][pos] = *(const s8v*)&hcat[(size_t)(n0 + qq) * (2 * H_) + pos];
  }
  __syncthreads();

  // A-frag (mt,ks): hs[mt*16 + (lane&15)][ks*32 + (lane>>4)*8]  (16B)
  const char* ar = (const char*)&hs[lane & 15][0] + ((lane >> 4) << 4);
  // B-frag (ks,f): pWb + (((ks*8 + w)*2 + f)*64 + lane)*16 bytes
  const char* bp = (const char*)pWb + (((size_t)w * 2) * 64 + lane) * 16;

  f4v acc[2][2];                     // [f][mt]
#pragma unroll
  for (int f = 0; f < 2; ++f)
#pragma unroll
    for (int mt = 0; mt < 2; ++mt) acc[f][mt] = (f4v){0.f, 0.f, 0.f, 0.f};

#pragma unroll 2
  for (int ks = 0; ks < 16; ++ks) {
    s8v a0 = *(const s8v*)(ar + ks * 64);
    s8v a1 = *(const s8v*)(ar + 16 * PROW * 2 + ks * 64);
    s8v b0 = *(const s8v*)(bp + (size_t)ks * 16384);          // f=0
    s8v b1 = *(const s8v*)(bp + (size_t)ks * 16384 + 1024);   // f=1
    acc[0][0] = __builtin_amdgcn_mfma_f32_16x16x32_bf16(a0, b0, acc[0][0], 0, 0, 0);
    acc[0][1] = __builtin_amdgcn_mfma_f32_16x16x32_bf16(a1, b0, acc[0][1], 0, 0, 0);
    acc[1][0] = __builtin_amdgcn_mfma_f32_16x16x32_bf16(a0, b1, acc[1][0], 0, 0, 0);
    acc[1][1] = __builtin_amdgcn_mfma_f32_16x16x32_bf16(a1, b1, acc[1][1], 0, 0, 0);
  }

  // epilogue: out[(n0+row)*256 + col] = acc + pb[col]
#pragma unroll
  for (int f = 0; f < 2; ++f) {
    const int col = (2 * w + f) * 16 + (lane & 15);
    const float bias = pb[col];
#pragma unroll
    for (int mt = 0; mt < 2; ++mt) {
#pragma unroll
      for (int reg = 0; reg < 4; ++reg) {
        int row = mt * 16 + ((lane >> 4) << 2) + reg;
        out[(size_t)(n0 + row) * H_ + col] = acc[f][mt][reg] + bias;
      }
    }
  }

  if (blockIdx.x == 0 && tid < B_) out[(size_t)NW * H_ + tid] = (float)W_;
}

// ---------------------------------------------------------------------------
extern "C" void kernel_launch(void* const* d_in, const int* in_sizes, int n_in,
                              void* d_out, int out_size, void* d_ws, size_t ws_size,
                              hipStream_t stream) {
  const int*   char_ids  = (const int*)  d_in[0];
  const int*   word_lens = (const int*)  d_in[1];
  const float* emb       = (const float*)d_in[2];
  const float* Wih_f     = (const float*)d_in[3];
  const float* Whh_f     = (const float*)d_in[4];
  const float* bih_f     = (const float*)d_in[5];
  const float* bhh_f     = (const float*)d_in[6];
  const float* Wih_b     = (const float*)d_in[7];
  const float* Whh_b     = (const float*)d_in[8];
  const float* bih_b     = (const float*)d_in[9];
  const float* bhh_b     = (const float*)d_in[10];
  const float* pW        = (const float*)d_in[11];
  const float* pb        = (const float*)d_in[12];
  float* out = (float*)d_out;

  // ws: [Bpack(fp8) 512KB][pWb(bf16) 256KB][ep4 512KB][perm 32KB][hcat 8.4MB]
  const size_t BPACK_BYTES = (size_t)2 * KS_ * 8 * 8 * 64 * 8;       // 512 KB
  const size_t PWB_BYTES   = (size_t)16 * 8 * 2 * 64 * 8 * 2;       // 256 KB
  const size_t EP4_BYTES   = (size_t)2 * V_ * 256 * 4 * 2;           // 512 KB
  unsigned char*  Bpack = (unsigned char*)d_ws;
  unsigned short* pWb   = (unsigned short*)((char*)d_ws + BPACK_BYTES);
  unsigned short* ep4   = (unsigned short*)((char*)d_ws + BPACK_BYTES + PWB_BYTES);
  int* perm = (int*)((char*)d_ws + BPACK_BYTES + PWB_BYTES + EP4_BYTES);
  unsigned short* hcat = (unsigned short*)((char*)d_ws + BPACK_BYTES + PWB_BYTES + EP4_BYTES + NW * sizeof(int));

  k_prep<<<dim3(337), dim3(1024), 0, stream>>>(word_lens, emb,
                                               Wih_f, bih_f, bhh_f,
                                               Wih_b, bih_b, bhh_b,
                                               Whh_f, Whh_b, pW,
                                               ep4, perm, Bpack, pWb);
  k_lstm<<<dim3(512), dim3(512), 0, stream>>>(char_ids, word_lens, perm, ep4, Bpack, hcat);
  k_proj<<<dim3(NW / 32), dim3(512), 0, stream>>>(hcat, pWb, pb, out);
}

// Round 19
// 320.243 us; speedup vs baseline: 4.2129x; 1.0389x over previous
//
#include <hip/hip_runtime.h>
#include <hip/hip_bf16.h>
#include <hip/hip_fp8.h>
#include <math.h>

// Problem constants
#define B_  64
#define W_  128
#define L_  32
#define V_  128
#define E_  128
#define H_  256
#define G4_ 1024      // 4*H
#define NW  8192      // B*W words
#define KS_ 8         // MFMA k-steps: h only (K=256), K=32 per fp8 MFMA
#define ROWB 264      // hL row bytes: 256 fp8 + 8 pad
#define HROW 264      // hLb row (ushorts): 256 bf16 + 8 pad
#define M_  32        // words per block
#define PROW 520      // k_proj LDS row (ushorts): 512 + 8 pad (1040B, odd*16)

typedef long i64;
typedef short s8v  __attribute__((ext_vector_type(8)));
typedef float f4v  __attribute__((ext_vector_type(4)));

static __device__ __forceinline__ float b2f(unsigned short u) {
  return __uint_as_float(((unsigned int)u) << 16);
}
static __device__ __forceinline__ unsigned char f2fp8(float f) {
  __hip_fp8_e4m3 t(f);          // OCP e4m3 on gfx950 (prep path only)
  return (unsigned char)t.__x;
}
static __device__ __forceinline__ unsigned short f2bfu(float f) {
  union { __hip_bfloat16 b; unsigned short u; } cv;
  cv.b = __float2bfloat16(f);
  return cv.u;
}
// fast sigmoid/tanh: v_exp + v_rcp (1-ulp), no IEEE div expansion
static __device__ __forceinline__ float sigm(float x) {
  return __builtin_amdgcn_rcpf(1.f + __expf(-x));
}
static __device__ __forceinline__ float tanh_(float x) {
  return __builtin_amdgcn_rcpf(1.f + __expf(-2.f * x)) * 2.f - 1.f;
}

// ---------------------------------------------------------------------------
// K_PREP: fused { embproj | sort | pack Whh | pack pW } — independent jobs.
// ---------------------------------------------------------------------------
#define NCHUNK 32
#define CHSZ  (NW / NCHUNK)
__global__ __launch_bounds__(1024) void k_prep(
    const int* __restrict__ word_lens,
    const float* __restrict__ emb,
    const float* __restrict__ Wih_f, const float* __restrict__ bih_f, const float* __restrict__ bhh_f,
    const float* __restrict__ Wih_b, const float* __restrict__ bih_b, const float* __restrict__ bhh_b,
    const float* __restrict__ Whh_f, const float* __restrict__ Whh_b,
    const float* __restrict__ pW,
    unsigned short* __restrict__ ep4, int* __restrict__ perm,
    unsigned char* __restrict__ Bpack, unsigned short* __restrict__ pWb) {
  const int bb  = blockIdx.x;
  const int tid = threadIdx.x;

  if (bb < 256) {
    // ---- embproj: block = (dir, v); thread = g = gate*256 + col ----
    int v   = bb & (V_ - 1);
    int dir = bb >> 7;
    const float* Wih = dir ? Wih_b : Wih_f;
    const float* b1  = dir ? bih_b : bih_f;
    const float* b2  = dir ? bhh_b : bhh_f;
    __shared__ float es[E_];
    if (tid < E_) es[tid] = emb[v * E_ + tid];
    __syncthreads();
    const float* wr = Wih + tid * E_;
    float a = 0.f;
#pragma unroll 4
    for (int k = 0; k < E_; k += 4) {
      float4 w4 = *(const float4*)(wr + k);
      float4 e4 = *(const float4*)(es + k);
      a += w4.x * e4.x + w4.y * e4.y + w4.z * e4.z + w4.w * e4.w;
    }
    int gate = tid >> 8, col = tid & 255;
    ep4[((((dir * V_ + v) << 8) + col) << 2) + gate] = f2bfu(a + b1[tid] + b2[tid]);
  } else if (bb == 256) {
    // ---- counting sort, descending ----
    __shared__ int cnt_s[NCHUNK][33];
    __shared__ int off_s[NCHUNK][33];
    const int ch  = tid >> 5;
    const int ln  = (tid & 31) + 1;   // 1..32
    const int base = ch * CHSZ;
    int c = 0;
    for (int i = 0; i < CHSZ; ++i) c += (word_lens[base + i] == ln);
    cnt_s[ch][ln] = c;
    __syncthreads();
    if (tid == 0) {
      int run = 0;
      for (int l = 32; l >= 1; --l)
        for (int c2 = 0; c2 < NCHUNK; ++c2) { off_s[c2][l] = run; run += cnt_s[c2][l]; }
    }
    __syncthreads();
    int ptr = off_s[ch][ln];
    for (int i = 0; i < CHSZ; ++i) {
      int wi = base + i;
      if (word_lens[wi] == ln) perm[ptr++] = wi;
    }
  } else if (bb <= 320) {
    // ---- Whh pack: 64 blocks x 16 tiles; tile = (dir,ks,w,f) ----
    int tile = (bb - 257) * 16 + (tid >> 6);
    const int lane = tid & 63;
    const int f    = tile & 7;
    const int w    = (tile >> 3) & 7;
    const int ks   = (tile >> 6) % KS_;
    const int dir  = tile / (64 * KS_);
    const float* Whh = dir ? Whh_b : Whh_f;
    const int u  = f >> 1, jj = f & 1;
    const int nt = u * 16 + 2 * w + jj;
    const int n  = nt * 16 + (lane & 15);
    const int k0 = ks * 32 + (lane >> 4) * 8;
    size_t base = ((((size_t)(dir * KS_ + ks) * 8 + w) * 8 + f) * 64 + lane) * 8;
#pragma unroll
    for (int j = 0; j < 8; ++j)
      Bpack[base + j] = f2fp8(Whh[n * H_ + k0 + j]);
  } else {
    // ---- pW pack (bf16): 16 blocks x 16 tiles; tile tp = ks*16 + nt ----
    int tp = (bb - 321) * 16 + (tid >> 6);
    const int lane = tid & 63;
    const int ks = tp >> 4;
    const int nt = tp & 15;
    const int w  = nt >> 1, f = nt & 1;
    const int n  = nt * 16 + (lane & 15);
    const int k0 = ks * 32 + (lane >> 4) * 8;
    size_t base = ((((size_t)ks * 8 + w) * 2 + f) * 64 + lane) * 8;
#pragma unroll
    for (int j = 0; j < 8; ++j)
      pWb[base + j] = f2bfu(pW[n * (2 * H_) + k0 + j]);
  }
}

// ---------------------------------------------------------------------------
// K2: fp8 MFMA BiLSTM recurrence — r17 geometry (proven: VGPR 64 + 64 AGPR,
// 2 blocks/CU, single barrier, fp8 dbuf hL) + EW micro-opts:
//   * jj-pair packed into ONE v_cvt_pk_fp8_f32 (HW cvt, halves cvt insts)
//   * fmaf for the c-state update
//   * s_setprio(1) around the MFMA cluster (2 out-of-phase blocks/CU ->
//     role diversity; T5 applies, unlike lockstep GEMM where it was null)
// C/D layout (verified m89): word = mt*16 + (lane>>4)*4 + r, col = lane&15.
// ---------------------------------------------------------------------------
__global__ __launch_bounds__(512, 4) void k_lstm(
    const int* __restrict__ char_ids, const int* __restrict__ word_lens,
    const int* __restrict__ perm, const unsigned short* __restrict__ ep4,
    const unsigned char* __restrict__ Bpack, unsigned short* __restrict__ hcat) {
  const int tid  = threadIdx.x;
  const int lane = tid & 63;
  const int w    = tid >> 6;       // wave 0..7
  const int bid  = blockIdx.x;
  const int q    = bid >> 7;
  const int dir  = q & 1;
  const int chunk = (bid < 256) ? (bid & 127) : ((q == 2) ? 511 - bid : 639 - bid);
  const int w0   = chunk * M_;

  __shared__ unsigned char  hL[2][M_][ROWB];  // 16.5 KB (fp8 h, double buffer)
  __shared__ unsigned short hLb[M_][HROW];    // 16.5 KB (bf16 h at freeze)
  __shared__ int ids_s[M_][L_ + 1];           // 4.2 KB
  __shared__ int len_s[M_];
  __shared__ int pw_s[M_];

  if (tid < M_) {
    int gw = perm[w0 + tid];
    pw_s[tid]  = gw;
    len_s[tid] = word_lens[gw];
  }
  __syncthreads();
  for (int i = tid; i < M_ * L_; i += 512) {
    int qq = i >> 5;
    ids_s[qq][i & 31] = char_ids[pw_s[qq] * L_ + (i & 31)];
  }
  for (int i = tid; i < M_ * ROWB / 4; i += 512) ((unsigned int*)hL[0])[i] = 0u;
  __syncthreads();

  const int mlen = len_s[0];   // descending sort -> first word is longest
  unsigned lrp[2];
#pragma unroll
  for (int mt = 0; mt < 2; ++mt) {
    int bw = mt * 16 + ((lane >> 4) << 2);
    lrp[mt] = (unsigned)len_s[bw] | ((unsigned)len_s[bw + 1] << 8) |
              ((unsigned)len_s[bw + 2] << 16) | ((unsigned)len_s[bw + 3] << 24);
  }

  const char* Bb0 = (const char*)Bpack + (size_t)dir * (KS_ * 8 * 8 * 64 * 8)
                    + (size_t)w * (8 * 64 * 8) + (size_t)lane * 8;
  const char* arA = (const char*)&hL[0][lane & 15][0] + ((lane >> 4) << 3);
  const char* arB = arA + M_ * ROWB;
  unsigned char* hwA = &hL[0][0][0];
  unsigned char* hwB = &hL[1][0][0];
  const ushort4* epv = (const ushort4*)ep4 + ((size_t)dir << 15);
  const int p0 = 2 * w * 16 + (lane & 15);
  const int g4 = (lane >> 4) << 2;

  float c_[2][2][4];
#pragma unroll
  for (int jj = 0; jj < 2; ++jj)
#pragma unroll
    for (int mt = 0; mt < 2; ++mt)
#pragma unroll
      for (int r = 0; r < 4; ++r) c_[jj][mt][r] = 0.f;

  for (int t = 0; t < mlen; ++t) {
    const char* ar = (t & 1) ? arB : arA;
    f4v acc[4][2][2];
#pragma unroll
    for (int u = 0; u < 4; ++u)
#pragma unroll
      for (int jj = 0; jj < 2; ++jj)
#pragma unroll
        for (int mt = 0; mt < 2; ++mt) acc[u][jj][mt] = (f4v){0.f, 0.f, 0.f, 0.f};

    const char* bp0 = Bb0;
    const char* bp1 = Bb0 + 2048;
    __builtin_amdgcn_s_setprio(1);
#pragma unroll 1
    for (int ks = 0; ks < KS_; ++ks) {
      i64 af0 = *(const i64*)(ar + ks * 32);
      i64 af1 = *(const i64*)(ar + 16 * ROWB + ks * 32);
      i64 b0 = *(const i64*)(bp0 + 0);
      i64 b1 = *(const i64*)(bp0 + 512);
      i64 b2 = *(const i64*)(bp0 + 1024);
      i64 b3 = *(const i64*)(bp0 + 1536);
      i64 b4 = *(const i64*)(bp1 + 0);
      i64 b5 = *(const i64*)(bp1 + 512);
      i64 b6 = *(const i64*)(bp1 + 1024);
      i64 b7 = *(const i64*)(bp1 + 1536);
      acc[0][0][0] = __builtin_amdgcn_mfma_f32_16x16x32_fp8_fp8(af0, b0, acc[0][0][0], 0, 0, 0);
      acc[0][0][1] = __builtin_amdgcn_mfma_f32_16x16x32_fp8_fp8(af1, b0, acc[0][0][1], 0, 0, 0);
      acc[0][1][0] = __builtin_amdgcn_mfma_f32_16x16x32_fp8_fp8(af0, b1, acc[0][1][0], 0, 0, 0);
      acc[0][1][1] = __builtin_amdgcn_mfma_f32_16x16x32_fp8_fp8(af1, b1, acc[0][1][1], 0, 0, 0);
      acc[1][0][0] = __builtin_amdgcn_mfma_f32_16x16x32_fp8_fp8(af0, b2, acc[1][0][0], 0, 0, 0);
      acc[1][0][1] = __builtin_amdgcn_mfma_f32_16x16x32_fp8_fp8(af1, b2, acc[1][0][1], 0, 0, 0);
      acc[1][1][0] = __builtin_amdgcn_mfma_f32_16x16x32_fp8_fp8(af0, b3, acc[1][1][0], 0, 0, 0);
      acc[1][1][1] = __builtin_amdgcn_mfma_f32_16x16x32_fp8_fp8(af1, b3, acc[1][1][1], 0, 0, 0);
      acc[2][0][0] = __builtin_amdgcn_mfma_f32_16x16x32_fp8_fp8(af0, b4, acc[2][0][0], 0, 0, 0);
      acc[2][0][1] = __builtin_amdgcn_mfma_f32_16x16x32_fp8_fp8(af1, b4, acc[2][0][1], 0, 0, 0);
      acc[2][1][0] = __builtin_amdgcn_mfma_f32_16x16x32_fp8_fp8(af0, b5, acc[2][1][0], 0, 0, 0);
      acc[2][1][1] = __builtin_amdgcn_mfma_f32_16x16x32_fp8_fp8(af1, b5, acc[2][1][1], 0, 0, 0);
      acc[3][0][0] = __builtin_amdgcn_mfma_f32_16x16x32_fp8_fp8(af0, b6, acc[3][0][0], 0, 0, 0);
      acc[3][0][1] = __builtin_amdgcn_mfma_f32_16x16x32_fp8_fp8(af1, b6, acc[3][0][1], 0, 0, 0);
      acc[3][1][0] = __builtin_amdgcn_mfma_f32_16x16x32_fp8_fp8(af0, b7, acc[3][1][0], 0, 0, 0);
      acc[3][1][1] = __builtin_amdgcn_mfma_f32_16x16x32_fp8_fp8(af1, b7, acc[3][1][1], 0, 0, 0);
      bp0 += 32768;
      bp1 += 32768;
    }
    __builtin_amdgcn_s_setprio(0);

    unsigned char* hwb = (t & 1) ? hwA : hwB;
#pragma unroll
    for (int mt = 0; mt < 2; ++mt) {
      ushort4 xc0[4], xc1[4];
      int act = 0, fin = 0;
#pragma unroll
      for (int r = 0; r < 4; ++r) {
        int len = (int)((lrp[mt] >> (8 * r)) & 255u);
        int tt  = dir ? max(len - 1 - t, 0) : t;
        int id  = ids_s[mt * 16 + g4 + r][tt];
        xc0[r] = epv[(id << 8) + p0];
        xc1[r] = epv[(id << 8) + p0 + 16];
        act |= (t < len)      ? (1 << r) : 0;
        fin |= (t == len - 1) ? (1 << r) : 0;
      }
#pragma unroll
      for (int r = 0; r < 4; ++r) {
        float cn2[2], hn2[2];
#pragma unroll
        for (int jj = 0; jj < 2; ++jj) {
          ushort4 xw = jj ? xc1[r] : xc0[r];
          float gi = acc[0][jj][mt][r] + b2f(xw.x);
          float gf = acc[1][jj][mt][r] + b2f(xw.y);
          float gg = acc[2][jj][mt][r] + b2f(xw.z);
          float go = acc[3][jj][mt][r] + b2f(xw.w);
          cn2[jj] = fmaf(sigm(gf), c_[jj][mt][r], sigm(gi) * tanh_(gg));
          hn2[jj] = sigm(go) * tanh_(cn2[jj]);
        }
        const int m = mt * 16 + g4 + r;
        const int p = p0;   // col of jj=0; jj=1 at p+16
        // one HW packed convert for both jj halves (bytes 0,1 of result)
        int pk = __builtin_amdgcn_cvt_pk_fp8_f32(hn2[0], hn2[1], 0, false);
        if ((act >> r) & 1) {
          c_[0][mt][r] = cn2[0];
          c_[1][mt][r] = cn2[1];
          hwb[m * ROWB + p]      = (unsigned char)(pk & 0xff);
          hwb[m * ROWB + p + 16] = (unsigned char)((pk >> 8) & 0xff);
        }
        if ((fin >> r) & 1) {
          hLb[m][p]      = f2bfu(hn2[0]);
          hLb[m][p + 16] = f2bfu(hn2[1]);
        }
      }
    }
    __syncthreads();
  }

  const int off = dir ? 0 : H_;
  for (int i = tid; i < M_ * H_ / 8; i += 512) {
    int qq  = i >> 5;
    int pos = (i & 31) << 3;
    s8v v = *(const s8v*)&hLb[qq][pos];
    *(s8v*)&hcat[(size_t)pw_s[qq] * (2 * H_) + off + pos] = v;
  }
}

// ---------------------------------------------------------------------------
// K3: wemb = hcat(bf16) @ pW^T + pb via bf16 MFMA (r18, unchanged).
// ---------------------------------------------------------------------------
__global__ __launch_bounds__(512) void k_proj(
    const unsigned short* __restrict__ hcat, const unsigned short* __restrict__ pWb,
    const float* __restrict__ pb, float* __restrict__ out) {
  const int tid  = threadIdx.x;
  const int lane = tid & 63;
  const int w    = tid >> 6;
  const int n0   = blockIdx.x * 32;

  __shared__ unsigned short hs[32][PROW];   // 33.3 KB
  for (int i = tid; i < 32 * (2 * H_) / 8; i += 512) {
    int qq  = i >> 6;
    int pos = (i & 63) << 3;
    *(s8v*)&hs[qq][pos] = *(const s8v*)&hcat[(size_t)(n0 + qq) * (2 * H_) + pos];
  }
  __syncthreads();

  const char* ar = (const char*)&hs[lane & 15][0] + ((lane >> 4) << 4);
  const char* bp = (const char*)pWb + (((size_t)w * 2) * 64 + lane) * 16;

  f4v acc[2][2];
#pragma unroll
  for (int f = 0; f < 2; ++f)
#pragma unroll
    for (int mt = 0; mt < 2; ++mt) acc[f][mt] = (f4v){0.f, 0.f, 0.f, 0.f};

#pragma unroll 2
  for (int ks = 0; ks < 16; ++ks) {
    s8v a0 = *(const s8v*)(ar + ks * 64);
    s8v a1 = *(const s8v*)(ar + 16 * PROW * 2 + ks * 64);
    s8v b0 = *(const s8v*)(bp + (size_t)ks * 16384);
    s8v b1 = *(const s8v*)(bp + (size_t)ks * 16384 + 1024);
    acc[0][0] = __builtin_amdgcn_mfma_f32_16x16x32_bf16(a0, b0, acc[0][0], 0, 0, 0);
    acc[0][1] = __builtin_amdgcn_mfma_f32_16x16x32_bf16(a1, b0, acc[0][1], 0, 0, 0);
    acc[1][0] = __builtin_amdgcn_mfma_f32_16x16x32_bf16(a0, b1, acc[1][0], 0, 0, 0);
    acc[1][1] = __builtin_amdgcn_mfma_f32_16x16x32_bf16(a1, b1, acc[1][1], 0, 0, 0);
  }

#pragma unroll
  for (int f = 0; f < 2; ++f) {
    const int col = (2 * w + f) * 16 + (lane & 15);
    const float bias = pb[col];
#pragma unroll
    for (int mt = 0; mt < 2; ++mt) {
#pragma unroll
      for (int reg = 0; reg < 4; ++reg) {
        int row = mt * 16 + ((lane >> 4) << 2) + reg;
        out[(size_t)(n0 + row) * H_ + col] = acc[f][mt][reg] + bias;
      }
    }
  }

  if (blockIdx.x == 0 && tid < B_) out[(size_t)NW * H_ + tid] = (float)W_;
}

// ---------------------------------------------------------------------------
extern "C" void kernel_launch(void* const* d_in, const int* in_sizes, int n_in,
                              void* d_out, int out_size, void* d_ws, size_t ws_size,
                              hipStream_t stream) {
  const int*   char_ids  = (const int*)  d_in[0];
  const int*   word_lens = (const int*)  d_in[1];
  const float* emb       = (const float*)d_in[2];
  const float* Wih_f     = (const float*)d_in[3];
  const float* Whh_f     = (const float*)d_in[4];
  const float* bih_f     = (const float*)d_in[5];
  const float* bhh_f     = (const float*)d_in[6];
  const float* Wih_b     = (const float*)d_in[7];
  const float* Whh_b     = (const float*)d_in[8];
  const float* bih_b     = (const float*)d_in[9];
  const float* bhh_b     = (const float*)d_in[10];
  const float* pW        = (const float*)d_in[11];
  const float* pb        = (const float*)d_in[12];
  float* out = (float*)d_out;

  // ws: [Bpack(fp8) 512KB][pWb(bf16) 256KB][ep4 512KB][perm 32KB][hcat 8.4MB]
  const size_t BPACK_BYTES = (size_t)2 * KS_ * 8 * 8 * 64 * 8;       // 512 KB
  const size_t PWB_BYTES   = (size_t)16 * 8 * 2 * 64 * 8 * 2;       // 256 KB
  const size_t EP4_BYTES   = (size_t)2 * V_ * 256 * 4 * 2;           // 512 KB
  unsigned char*  Bpack = (unsigned char*)d_ws;
  unsigned short* pWb   = (unsigned short*)((char*)d_ws + BPACK_BYTES);
  unsigned short* ep4   = (unsigned short*)((char*)d_ws + BPACK_BYTES + PWB_BYTES);
  int* perm = (int*)((char*)d_ws + BPACK_BYTES + PWB_BYTES + EP4_BYTES);
  unsigned short* hcat = (unsigned short*)((char*)d_ws + BPACK_BYTES + PWB_BYTES + EP4_BYTES + NW * sizeof(int));

  k_prep<<<dim3(337), dim3(1024), 0, stream>>>(word_lens, emb,
                                               Wih_f, bih_f, bhh_f,
                                               Wih_b, bih_b, bhh_b,
                                               Whh_f, Whh_b, pW,
                                               ep4, perm, Bpack, pWb);
  k_lstm<<<dim3(512), dim3(512), 0, stream>>>(char_ids, word_lens, perm, ep4, Bpack, hcat);
  k_proj<<<dim3(NW / 32), dim3(512), 0, stream>>>(hcat, pWb, pb, out);
}